// Round 2
// baseline (2000.692 us; speedup 1.0000x reference)
//
#include <hip/hip_runtime.h>
#include <math.h>

// ---------------- problem constants ----------------
#define NTREES 128
#define NPT 127
#define NNODES (NTREES*NPT)      // 16256
#define EUP (NTREES*(NPT-1))     // 16128
#define NEDGE (2*EUP)            // 32256
#define HDIM 450
#define HP 512                   // padded hidden
#define LMAX 8192
#define NLVL 12

// ---------------- GEMM tile constants ----------------
#define TM 64
#define TN 64
#define TK 32
#define ASTRIDE 68               // padded LDS stride

__device__ __forceinline__ float sigmoidf_(float x) { return 1.f / (1.f + expf(-x)); }

// ============== zero-fill (replaces hipMemsetAsync) ==============
__global__ void zero_ws(float4* __restrict__ p, int n4) {
  int i = blockIdx.x * 256 + threadIdx.x;
  int stride = gridDim.x * 256;
  for (; i < n4; i += stride) p[i] = make_float4(0.f, 0.f, 0.f, 0.f);
}

// ============== prep: zero-padded weight copies ==============
// Wpre[512][1536] = [Wz_top|Wh_top|Wr]; Wzb/Whb[512][512] = bottom halves;
// Urp[512][512]; Wgp[1024][512]; biasp[4][512] = bz,bh,bur,bg
__global__ void prep_pad(const float* __restrict__ Wz, const float* __restrict__ Wh,
                         const float* __restrict__ Wr, const float* __restrict__ Ur,
                         const float* __restrict__ Wg,
                         const float* __restrict__ bz, const float* __restrict__ bh,
                         const float* __restrict__ bur, const float* __restrict__ bg,
                         float* __restrict__ Wpre, float* __restrict__ Wzb,
                         float* __restrict__ Whb, float* __restrict__ Urp,
                         float* __restrict__ Wgp, float* __restrict__ biasp) {
  int idx = blockIdx.x * 256 + threadIdx.x;
  if (idx < 512 * 1536) {                        // Wpre
    int k = idx / 1536, n = idx - k * 1536;
    int sel = n >> 9, j = n & 511;
    float v = 0.f;
    if (k < HDIM && j < HDIM) {
      const float* W = (sel == 0) ? Wz : (sel == 1) ? Wh : Wr;
      v = W[k * HDIM + j];
    }
    Wpre[idx] = v;
    return;
  }
  idx -= 512 * 1536;
  if (idx < 3 * 262144) {                        // Wzb, Whb, Urp
    int which = idx >> 18; int r = idx & 262143;
    int k = r >> 9, j = r & 511;
    float v = 0.f;
    if (k < HDIM && j < HDIM)
      v = (which == 0) ? Wz[(HDIM + k) * HDIM + j]
        : (which == 1) ? Wh[(HDIM + k) * HDIM + j]
                       : Ur[k * HDIM + j];
    ((which == 0) ? Wzb : (which == 1) ? Whb : Urp)[r] = v;
    return;
  }
  idx -= 3 * 262144;
  if (idx < 1024 * 512) {                        // Wgp
    int k = idx >> 9, j = idx & 511;
    float v = 0.f;
    if (j < HDIM) {
      if (k < HDIM) v = Wg[k * HDIM + j];
      else if (k >= HP && (k - HP) < HDIM) v = Wg[(HDIM + k - HP) * HDIM + j];
    }
    Wgp[idx] = v;
    return;
  }
  idx -= 1024 * 512;
  if (idx < 4 * HP) {                            // biases
    int which = idx >> 9, j = idx & 511;
    float v = 0.f;
    if (j < HDIM)
      v = ((which == 0) ? bz : (which == 1) ? bh : (which == 2) ? bur : bg)[j];
    biasp[idx] = v;
  }
}

// gather one float4 of the padded embedding row (emb rows: 450 floats, 8B-aligned)
__device__ __forceinline__ float4 emb_f4(const float* __restrict__ er, int col) {
  float4 av = make_float4(0.f, 0.f, 0.f, 0.f);
  if (col < 448) {
    float2 p0 = *(const float2*)(er + col);
    float2 p1 = *(const float2*)(er + col + 2);
    av.x = p0.x; av.y = p0.y; av.z = p1.x; av.w = p1.y;
  } else if (col == 448) {
    av.x = er[448]; av.y = er[449];
  }
  return av;
}

// ============== Xpre GEMM: [Xz|Xh|Xr] = x @ Wpre (x gathered inline) ==============
__global__ __launch_bounds__(256, 4) void gemm_pre(
    const int* __restrict__ wid, const float* __restrict__ emb,
    const float* __restrict__ B, float* __restrict__ Xzh, float* __restrict__ Xr) {
  __shared__ __align__(16) float As[TK][ASTRIDE];
  __shared__ __align__(16) float Bs[TK][TN];
  __shared__ int wid_s[TM];
  int tid = threadIdx.x;
  int n0 = blockIdx.x * TN;
  int m0 = blockIdx.y * TM;
  if (tid < TM) wid_s[tid] = wid[m0 + tid];
  __syncthreads();
  int tx = tid & 15, ty = tid >> 4;
  float acc[4][4] = {};
  for (int kt = 0; kt < HP; kt += TK) {
#pragma unroll
    for (int q = 0; q < 2; ++q) {
      int slot = q * 256 + tid;
      int row = slot >> 3, cg = slot & 7;
      float4 av = emb_f4(emb + (size_t)wid_s[row] * HDIM, kt + cg * 4);
      As[cg * 4 + 0][row] = av.x;
      As[cg * 4 + 1][row] = av.y;
      As[cg * 4 + 2][row] = av.z;
      As[cg * 4 + 3][row] = av.w;
      int brow = slot >> 4, bcg = slot & 15;
      *(float4*)&Bs[brow][bcg * 4] =
          *(const float4*)(B + (size_t)(kt + brow) * 1536 + n0 + bcg * 4);
    }
    __syncthreads();
#pragma unroll 8
    for (int kk = 0; kk < TK; ++kk) {
      float a[4], b[4];
      *(float4*)a = *(const float4*)&As[kk][ty * 4];
      *(float4*)b = *(const float4*)&Bs[kk][tx * 4];
#pragma unroll
      for (int i = 0; i < 4; ++i)
#pragma unroll
        for (int j = 0; j < 4; ++j) acc[i][j] = fmaf(a[i], b[j], acc[i][j]);
    }
    __syncthreads();
  }
#pragma unroll
  for (int i = 0; i < 4; ++i) {
    int row = m0 + ty * 4 + i;
    float4 v = make_float4(acc[i][0], acc[i][1], acc[i][2], acc[i][3]);
    if (n0 < 1024)
      *(float4*)(Xzh + (size_t)row * 1024 + n0 + tx * 4) = v;
    else
      *(float4*)(Xr + (size_t)row * HP + (n0 - 1024) + tx * 4) = v;
  }
}

// ============== level 0 (leaf children): s=0 -> m_new = z*mt, elementwise ==============
__global__ void leaf_lvl0(const int* __restrict__ sched0, const int* __restrict__ src,
                          const float* __restrict__ Xzh, const float* __restrict__ biasp,
                          float* __restrict__ mup) {
  int gid = blockIdx.x * 256 + threadIdx.x;   // 8192 * 128
  int r = gid >> 7, g = gid & 127;
  int e = sched0[r];
  int se = src[e];
  int col = g * 4;
  float4 xz = *(const float4*)(Xzh + (size_t)se * 1024 + col);
  float4 xh = *(const float4*)(Xzh + (size_t)se * 1024 + 512 + col);
  float4 bz = *(const float4*)(biasp + col);
  float4 bh = *(const float4*)(biasp + 512 + col);
  float4 o;
  o.x = sigmoidf_(xz.x + bz.x) * tanhf(xh.x + bh.x);
  o.y = sigmoidf_(xz.y + bz.y) * tanhf(xh.y + bh.y);
  o.z = sigmoidf_(xz.z + bz.z) * tanhf(xh.z + bh.z);
  o.w = sigmoidf_(xz.w + bz.w) * tanhf(xh.w + bh.w);
  *(float4*)(mup + (size_t)e * HP + col) = o;
}

// ============== up-level GEMM1: s=node_m[se], arm=node_rm[se] (rev terms = 0) ==============
__global__ __launch_bounds__(256, 4) void gemm_lvl1_up(
    const int* __restrict__ schedrow, const int* __restrict__ src,
    const float* __restrict__ node_m, const float* __restrict__ node_rm,
    const float* __restrict__ Xzh, const float* __restrict__ Wzb,
    const float* __restrict__ Whb, const float* __restrict__ biasp,
    float* __restrict__ mup) {
  __shared__ __align__(16) float As[TK][ASTRIDE];
  __shared__ __align__(16) float Aa[TK][ASTRIDE];
  __shared__ __align__(16) float Bz[TK][TN];
  __shared__ __align__(16) float Bt[TK][TN];
  __shared__ int se_s[TM], e_s[TM];
  int tid = threadIdx.x;
  int n0 = blockIdx.x * TN;
  int m0 = blockIdx.y * TM;
  if (tid < TM) {
    int e = schedrow[m0 + tid];
    e_s[tid] = e;
    se_s[tid] = src[e];
  }
  __syncthreads();
  int tx = tid & 15, ty = tid >> 4;
  float accZ[4][4] = {};
  float accT[4][4] = {};
  for (int kt = 0; kt < HP; kt += TK) {
#pragma unroll
    for (int q = 0; q < 2; ++q) {
      int slot = q * 256 + tid;
      int row = slot >> 3, cg = slot & 7;
      int se = se_s[row];
      float4 a = *(const float4*)(node_m + (size_t)se * HP + kt + cg * 4);
      As[cg * 4 + 0][row] = a.x;
      As[cg * 4 + 1][row] = a.y;
      As[cg * 4 + 2][row] = a.z;
      As[cg * 4 + 3][row] = a.w;
      float4 c = *(const float4*)(node_rm + (size_t)se * HP + kt + cg * 4);
      Aa[cg * 4 + 0][row] = c.x;
      Aa[cg * 4 + 1][row] = c.y;
      Aa[cg * 4 + 2][row] = c.z;
      Aa[cg * 4 + 3][row] = c.w;
      int brow = slot >> 4, bcg = slot & 15;
      *(float4*)&Bz[brow][bcg * 4] =
          *(const float4*)(Wzb + (size_t)(kt + brow) * HP + n0 + bcg * 4);
      *(float4*)&Bt[brow][bcg * 4] =
          *(const float4*)(Whb + (size_t)(kt + brow) * HP + n0 + bcg * 4);
    }
    __syncthreads();
#pragma unroll 4
    for (int kk = 0; kk < TK; ++kk) {
      float as_[4], aa_[4], bz_[4], bt_[4];
      *(float4*)as_ = *(const float4*)&As[kk][ty * 4];
      *(float4*)aa_ = *(const float4*)&Aa[kk][ty * 4];
      *(float4*)bz_ = *(const float4*)&Bz[kk][tx * 4];
      *(float4*)bt_ = *(const float4*)&Bt[kk][tx * 4];
#pragma unroll
      for (int i = 0; i < 4; ++i)
#pragma unroll
        for (int j = 0; j < 4; ++j) {
          accZ[i][j] = fmaf(as_[i], bz_[j], accZ[i][j]);
          accT[i][j] = fmaf(aa_[i], bt_[j], accT[i][j]);
        }
    }
    __syncthreads();
  }
  int col = n0 + tx * 4;
#pragma unroll
  for (int i = 0; i < 4; ++i) {
    int l = ty * 4 + i;
    int e = e_s[l], se = se_s[l];
    float xz[4], xh[4], sv[4], bzv[4], bhv[4], outv[4];
    *(float4*)xz = *(const float4*)(Xzh + (size_t)se * 1024 + col);
    *(float4*)xh = *(const float4*)(Xzh + (size_t)se * 1024 + 512 + col);
    *(float4*)sv = *(const float4*)(node_m + (size_t)se * HP + col);
    *(float4*)bzv = *(const float4*)(biasp + col);
    *(float4*)bhv = *(const float4*)(biasp + 512 + col);
#pragma unroll
    for (int j = 0; j < 4; ++j) {
      float z = sigmoidf_(accZ[i][j] + xz[j] + bzv[j]);
      float t = tanhf(accT[i][j] + xh[j] + bhv[j]);
      outv[j] = (1.f - z) * sv[j] + z * t;
    }
    *(float4*)(mup + (size_t)e * HP + col) = *(float4*)outv;
  }
}

// ============== down-level GEMM1: s=node_m[se]-mup[rev], arm=node_rm[se]-rmup[rev] ==============
__global__ __launch_bounds__(256, 4) void gemm_lvl1_down(
    const int* __restrict__ schedrow, const int* __restrict__ src,
    const float* __restrict__ node_m, const float* __restrict__ node_rm,
    const float* __restrict__ mup, const float* __restrict__ rmup,
    const float* __restrict__ Xzh, const float* __restrict__ Wzb,
    const float* __restrict__ Whb, const float* __restrict__ biasp,
    float* __restrict__ dtmp) {
  __shared__ __align__(16) float As[TK][ASTRIDE];
  __shared__ __align__(16) float Aa[TK][ASTRIDE];
  __shared__ __align__(16) float Bz[TK][TN];
  __shared__ __align__(16) float Bt[TK][TN];
  __shared__ int se_s[TM], eu_s[TM];
  int tid = threadIdx.x;
  int n0 = blockIdx.x * TN;
  int m0 = blockIdx.y * TM;
  if (tid < TM) {
    int e = schedrow[m0 + tid];
    eu_s[tid] = e - EUP;          // rev[e] = e - EUP for down edges
    se_s[tid] = src[e];
  }
  __syncthreads();
  int tx = tid & 15, ty = tid >> 4;
  float accZ[4][4] = {};
  float accT[4][4] = {};
  for (int kt = 0; kt < HP; kt += TK) {
#pragma unroll
    for (int q = 0; q < 2; ++q) {
      int slot = q * 256 + tid;
      int row = slot >> 3, cg = slot & 7;
      int se = se_s[row], eu = eu_s[row];
      float4 a = *(const float4*)(node_m + (size_t)se * HP + kt + cg * 4);
      float4 b = *(const float4*)(mup + (size_t)eu * HP + kt + cg * 4);
      As[cg * 4 + 0][row] = a.x - b.x;
      As[cg * 4 + 1][row] = a.y - b.y;
      As[cg * 4 + 2][row] = a.z - b.z;
      As[cg * 4 + 3][row] = a.w - b.w;
      float4 c = *(const float4*)(node_rm + (size_t)se * HP + kt + cg * 4);
      float4 d = *(const float4*)(rmup + (size_t)eu * HP + kt + cg * 4);
      Aa[cg * 4 + 0][row] = c.x - d.x;
      Aa[cg * 4 + 1][row] = c.y - d.y;
      Aa[cg * 4 + 2][row] = c.z - d.z;
      Aa[cg * 4 + 3][row] = c.w - d.w;
      int brow = slot >> 4, bcg = slot & 15;
      *(float4*)&Bz[brow][bcg * 4] =
          *(const float4*)(Wzb + (size_t)(kt + brow) * HP + n0 + bcg * 4);
      *(float4*)&Bt[brow][bcg * 4] =
          *(const float4*)(Whb + (size_t)(kt + brow) * HP + n0 + bcg * 4);
    }
    __syncthreads();
#pragma unroll 4
    for (int kk = 0; kk < TK; ++kk) {
      float as_[4], aa_[4], bz_[4], bt_[4];
      *(float4*)as_ = *(const float4*)&As[kk][ty * 4];
      *(float4*)aa_ = *(const float4*)&Aa[kk][ty * 4];
      *(float4*)bz_ = *(const float4*)&Bz[kk][tx * 4];
      *(float4*)bt_ = *(const float4*)&Bt[kk][tx * 4];
#pragma unroll
      for (int i = 0; i < 4; ++i)
#pragma unroll
        for (int j = 0; j < 4; ++j) {
          accZ[i][j] = fmaf(as_[i], bz_[j], accZ[i][j]);
          accT[i][j] = fmaf(aa_[i], bt_[j], accT[i][j]);
        }
    }
    __syncthreads();
  }
  int col = n0 + tx * 4;
#pragma unroll
  for (int i = 0; i < 4; ++i) {
    int l = ty * 4 + i;
    int se = se_s[l], eu = eu_s[l];
    float xz[4], xh[4], nm[4], mv[4], bzv[4], bhv[4], outv[4];
    *(float4*)xz = *(const float4*)(Xzh + (size_t)se * 1024 + col);
    *(float4*)xh = *(const float4*)(Xzh + (size_t)se * 1024 + 512 + col);
    *(float4*)nm = *(const float4*)(node_m + (size_t)se * HP + col);
    *(float4*)mv = *(const float4*)(mup + (size_t)eu * HP + col);
    *(float4*)bzv = *(const float4*)(biasp + col);
    *(float4*)bhv = *(const float4*)(biasp + 512 + col);
#pragma unroll
    for (int j = 0; j < 4; ++j) {
      float z = sigmoidf_(accZ[i][j] + xz[j] + bzv[j]);
      float t = tanhf(accT[i][j] + xh[j] + bhv[j]);
      float s = nm[j] - mv[j];
      outv[j] = (1.f - z) * s + z * t;
    }
    *(float4*)(dtmp + (size_t)(m0 + l) * HP + col) = *(float4*)outv;
  }
}

// ============== up-level GEMM2: r, rmup; node accumulators (pair store) ==============
__global__ __launch_bounds__(256, 4) void gemm_lvl2_up(
    const int* __restrict__ schedrow, const int* __restrict__ dst,
    const float* __restrict__ mup, float* __restrict__ rmup,
    float* __restrict__ node_m, float* __restrict__ node_rm,
    const float* __restrict__ Xr, const float* __restrict__ Urp,
    const float* __restrict__ biasp) {
  __shared__ __align__(16) float As[TK][ASTRIDE];
  __shared__ __align__(16) float Bs[TK][TN];
  __shared__ int e_s[TM], de_s[TM];
  int tid = threadIdx.x;
  int n0 = blockIdx.x * TN;
  int m0 = blockIdx.y * TM;
  if (tid < TM) {
    int e = schedrow[m0 + tid];
    e_s[tid] = e;
    de_s[tid] = dst[e];
  }
  __syncthreads();
  int tx = tid & 15, ty = tid >> 4;
  float acc[4][4] = {};
  for (int kt = 0; kt < HP; kt += TK) {
#pragma unroll
    for (int q = 0; q < 2; ++q) {
      int slot = q * 256 + tid;
      int row = slot >> 3, cg = slot & 7;
      float4 a = *(const float4*)(mup + (size_t)e_s[row] * HP + kt + cg * 4);
      As[cg * 4 + 0][row] = a.x;
      As[cg * 4 + 1][row] = a.y;
      As[cg * 4 + 2][row] = a.z;
      As[cg * 4 + 3][row] = a.w;
      int brow = slot >> 4, bcg = slot & 15;
      *(float4*)&Bs[brow][bcg * 4] =
          *(const float4*)(Urp + (size_t)(kt + brow) * HP + n0 + bcg * 4);
    }
    __syncthreads();
#pragma unroll 8
    for (int kk = 0; kk < TK; ++kk) {
      float a[4], b[4];
      *(float4*)a = *(const float4*)&As[kk][ty * 4];
      *(float4*)b = *(const float4*)&Bs[kk][tx * 4];
#pragma unroll
      for (int i = 0; i < 4; ++i)
#pragma unroll
        for (int j = 0; j < 4; ++j) acc[i][j] = fmaf(a[i], b[j], acc[i][j]);
    }
    __syncthreads();
  }
  int col = n0 + tx * 4;
  float mv[4][4], rmv[4][4];
#pragma unroll
  for (int i = 0; i < 4; ++i) {
    int l = ty * 4 + i;
    int e = e_s[l], de = de_s[l];
    float xr[4], bb[4];
    *(float4*)xr = *(const float4*)(Xr + (size_t)de * HP + col);
    *(float4*)bb = *(const float4*)(biasp + 2 * HP + col);
    *(float4*)&mv[i][0] = *(const float4*)(mup + (size_t)e * HP + col);
#pragma unroll
    for (int j = 0; j < 4; ++j) {
      float r = sigmoidf_(acc[i][j] + xr[j] + bb[j]);
      rmv[i][j] = r * mv[i][j];
    }
    *(float4*)(rmup + (size_t)e * HP + col) = *(float4*)&rmv[i][0];
  }
  // adjacent schedule rows share the same parent; parent untouched before -> store
#pragma unroll
  for (int i = 0; i < 4; i += 2) {
    int de = de_s[ty * 4 + i];
    float cm[4], cr[4];
#pragma unroll
    for (int j = 0; j < 4; ++j) {
      cm[j] = mv[i][j] + mv[i + 1][j];
      cr[j] = rmv[i][j] + rmv[i + 1][j];
    }
    *(float4*)(node_m + (size_t)de * HP + col) = *(float4*)cm;
    *(float4*)(node_rm + (size_t)de * HP + col) = *(float4*)cr;
  }
}

// ============== down-level GEMM2: r; node accumulators (+=), no per-edge store ==============
__global__ __launch_bounds__(256, 4) void gemm_lvl2_down(
    const int* __restrict__ schedrow, const int* __restrict__ dst,
    const float* __restrict__ dtmp,
    float* __restrict__ node_m, float* __restrict__ node_rm,
    const float* __restrict__ Xr, const float* __restrict__ Urp,
    const float* __restrict__ biasp) {
  __shared__ __align__(16) float As[TK][ASTRIDE];
  __shared__ __align__(16) float Bs[TK][TN];
  __shared__ int de_s[TM];
  int tid = threadIdx.x;
  int n0 = blockIdx.x * TN;
  int m0 = blockIdx.y * TM;
  if (tid < TM) de_s[tid] = dst[schedrow[m0 + tid]];
  __syncthreads();
  int tx = tid & 15, ty = tid >> 4;
  float acc[4][4] = {};
  for (int kt = 0; kt < HP; kt += TK) {
#pragma unroll
    for (int q = 0; q < 2; ++q) {
      int slot = q * 256 + tid;
      int row = slot >> 3, cg = slot & 7;
      float4 a = *(const float4*)(dtmp + (size_t)(m0 + row) * HP + kt + cg * 4);
      As[cg * 4 + 0][row] = a.x;
      As[cg * 4 + 1][row] = a.y;
      As[cg * 4 + 2][row] = a.z;
      As[cg * 4 + 3][row] = a.w;
      int brow = slot >> 4, bcg = slot & 15;
      *(float4*)&Bs[brow][bcg * 4] =
          *(const float4*)(Urp + (size_t)(kt + brow) * HP + n0 + bcg * 4);
    }
    __syncthreads();
#pragma unroll 8
    for (int kk = 0; kk < TK; ++kk) {
      float a[4], b[4];
      *(float4*)a = *(const float4*)&As[kk][ty * 4];
      *(float4*)b = *(const float4*)&Bs[kk][tx * 4];
#pragma unroll
      for (int i = 0; i < 4; ++i)
#pragma unroll
        for (int j = 0; j < 4; ++j) acc[i][j] = fmaf(a[i], b[j], acc[i][j]);
    }
    __syncthreads();
  }
  int col = n0 + tx * 4;
#pragma unroll
  for (int i = 0; i < 4; ++i) {
    int l = ty * 4 + i;
    int de = de_s[l];
    float xr[4], bb[4], mv[4], cm[4], cr[4];
    *(float4*)xr = *(const float4*)(Xr + (size_t)de * HP + col);
    *(float4*)bb = *(const float4*)(biasp + 2 * HP + col);
    *(float4*)mv = *(const float4*)(dtmp + (size_t)(m0 + l) * HP + col);
    *(float4*)cm = *(const float4*)(node_m + (size_t)de * HP + col);
    *(float4*)cr = *(const float4*)(node_rm + (size_t)de * HP + col);
#pragma unroll
    for (int j = 0; j < 4; ++j) {
      float r = sigmoidf_(acc[i][j] + xr[j] + bb[j]);
      cm[j] += mv[j];
      cr[j] += r * mv[j];
    }
    *(float4*)(node_m + (size_t)de * HP + col) = *(float4*)cm;
    *(float4*)(node_rm + (size_t)de * HP + col) = *(float4*)cr;
  }
}

// ============== final GEMM: h = relu([x, node_m] @ Wg + bg) ==============
__global__ __launch_bounds__(256, 4) void gemm_final(
    const int* __restrict__ wid, const float* __restrict__ emb,
    const float* __restrict__ node_m, const float* __restrict__ Wgp,
    const float* __restrict__ biasp, float* __restrict__ out) {
  __shared__ __align__(16) float As[TK][ASTRIDE];
  __shared__ __align__(16) float Bs[TK][TN];
  __shared__ int wid_s[TM];
  int tid = threadIdx.x;
  int n0 = blockIdx.x * TN;
  int m0 = blockIdx.y * TM;
  if (tid < TM) wid_s[tid] = wid[m0 + tid];
  __syncthreads();
  int tx = tid & 15, ty = tid >> 4;
  float acc[4][4] = {};
  for (int kt = 0; kt < 2 * HP; kt += TK) {
#pragma unroll
    for (int q = 0; q < 2; ++q) {
      int slot = q * 256 + tid;
      int row = slot >> 3, cg = slot & 7;
      float4 av;
      if (kt < HP) {
        av = emb_f4(emb + (size_t)wid_s[row] * HDIM, kt + cg * 4);
      } else {
        av = *(const float4*)(node_m + (size_t)(m0 + row) * HP + (kt - HP) + cg * 4);
      }
      As[cg * 4 + 0][row] = av.x;
      As[cg * 4 + 1][row] = av.y;
      As[cg * 4 + 2][row] = av.z;
      As[cg * 4 + 3][row] = av.w;
      int brow = slot >> 4, bcg = slot & 15;
      *(float4*)&Bs[brow][bcg * 4] =
          *(const float4*)(Wgp + (size_t)(kt + brow) * HP + n0 + bcg * 4);
    }
    __syncthreads();
#pragma unroll 8
    for (int kk = 0; kk < TK; ++kk) {
      float a[4], b[4];
      *(float4*)a = *(const float4*)&As[kk][ty * 4];
      *(float4*)b = *(const float4*)&Bs[kk][tx * 4];
#pragma unroll
      for (int i = 0; i < 4; ++i)
#pragma unroll
        for (int j = 0; j < 4; ++j) acc[i][j] = fmaf(a[i], b[j], acc[i][j]);
    }
    __syncthreads();
  }
#pragma unroll
  for (int i = 0; i < 4; ++i) {
    int row = m0 + ty * 4 + i;
#pragma unroll
    for (int j = 0; j < 4; ++j) {
      int c = n0 + tx * 4 + j;
      if (c < HDIM) {
        float v = acc[i][j] + biasp[3 * HP + c];
        out[(size_t)row * HDIM + c] = v > 0.f ? v : 0.f;
      }
    }
  }
}

// ====================== host launcher ======================
extern "C" void kernel_launch(void* const* d_in, const int* in_sizes, int n_in,
                              void* d_out, int out_size, void* d_ws, size_t ws_size,
                              hipStream_t stream) {
  const int* wid = (const int*)d_in[0];
  const int* src = (const int*)d_in[1];
  const int* dst = (const int*)d_in[2];
  const int* sched = (const int*)d_in[4];
  const float* emb = (const float*)d_in[5];
  const float* Wz = (const float*)d_in[6];
  const float* bz = (const float*)d_in[7];
  const float* Wr = (const float*)d_in[8];
  const float* Ur = (const float*)d_in[9];
  const float* bur = (const float*)d_in[10];
  const float* Wh = (const float*)d_in[11];
  const float* bh = (const float*)d_in[12];
  const float* Wg = (const float*)d_in[13];
  const float* bg = (const float*)d_in[14];
  float* out = (float*)d_out;
  float* ws = (float*)d_ws;

  // ---- workspace layout (floats), total 254,550,016 bytes ----
  size_t o = 0;
  float* Xzh = ws + o;     o += (size_t)NNODES * 1024;   // 16,646,144
  float* Xr = ws + o;      o += (size_t)NNODES * HP;     //  8,323,072
  float* node_m = ws + o;  o += (size_t)NNODES * HP;
  float* node_rm = ws + o; o += (size_t)NNODES * HP;
  float* mup = ws + o;     o += (size_t)EUP * HP;        //  8,257,536
  float* rmup = ws + o;    o += (size_t)EUP * HP;
  float* Wzb = ws + o;     o += (size_t)HP * HP;
  float* Whb = ws + o;     o += (size_t)HP * HP;
  float* Urp = ws + o;     o += (size_t)HP * HP;
  float* Wgp = ws + o;     o += (size_t)2 * HP * HP;
  float* biasp = ws + o;   o += (size_t)4 * HP;
  float* dtmp = ws + o;    o += (size_t)LMAX * HP;       // 4,194,304 (dtmp ∪ Wpre)
  float* Wpre = dtmp;      // Wpre (512x1536) lives in dtmp region; disjoint lifetime

  size_t need_bytes = o * sizeof(float);
  if (ws_size < need_bytes) return;  // diagnostic: fail with finite absmax, no fault

  // zero node accumulators + up-edge message buffers (contiguous region)
  size_t zf = (size_t)2 * NNODES * HP + (size_t)2 * EUP * HP;  // 33,161,216 floats
  zero_ws<<<2048, 256, 0, stream>>>((float4*)node_m, (int)(zf / 4));

  int prep_elems = 512 * 1536 + 3 * 262144 + 1024 * 512 + 4 * HP;
  prep_pad<<<(prep_elems + 255) / 256, 256, 0, stream>>>(
      Wz, Wh, Wr, Ur, Wg, bz, bh, bur, bg, Wpre, Wzb, Whb, Urp, Wgp, biasp);

  gemm_pre<<<dim3(1536 / TN, NNODES / TM), 256, 0, stream>>>(wid, emb, Wpre, Xzh, Xr);

  for (int lvl = 0; lvl < NLVL; ++lvl) {
    int L = (lvl < 6) ? (LMAX >> lvl) : (256 << (lvl - 6));
    const int* schedrow = sched + (size_t)lvl * LMAX;
    if (lvl == 0) {
      leaf_lvl0<<<4096, 256, 0, stream>>>(schedrow, src, Xzh, biasp, mup);
    } else if (lvl < 6) {
      gemm_lvl1_up<<<dim3(HP / TN, L / TM), 256, 0, stream>>>(
          schedrow, src, node_m, node_rm, Xzh, Wzb, Whb, biasp, mup);
    } else {
      gemm_lvl1_down<<<dim3(HP / TN, L / TM), 256, 0, stream>>>(
          schedrow, src, node_m, node_rm, mup, rmup, Xzh, Wzb, Whb, biasp, dtmp);
    }
    if (lvl < 6) {
      gemm_lvl2_up<<<dim3(HP / TN, L / TM), 256, 0, stream>>>(
          schedrow, dst, mup, rmup, node_m, node_rm, Xr, Urp, biasp);
    } else {
      gemm_lvl2_down<<<dim3(HP / TN, L / TM), 256, 0, stream>>>(
          schedrow, dst, dtmp, node_m, node_rm, Xr, Urp, biasp);
    }
  }

  gemm_final<<<dim3(HP / TN, NNODES / TM), 256, 0, stream>>>(
      wid, emb, node_m, Wgp, biasp, out);
}

// Round 3
// 778.792 us; speedup vs baseline: 2.5690x; 2.5690x over previous
//
#include <hip/hip_runtime.h>
#include <math.h>

// ---------------- problem constants ----------------
#define NTREES 128
#define NPT 127
#define NNODES (NTREES*NPT)      // 16256
#define EUP (NTREES*(NPT-1))     // 16128
#define HDIM 450
#define HP 512
#define LMAX 8192
#define NLVL 12

typedef unsigned short u16;
typedef __attribute__((ext_vector_type(8))) short bf16x8;
typedef __attribute__((ext_vector_type(4))) float f32x4;

__device__ __forceinline__ float sigmoidf_(float x) { return 1.f / (1.f + expf(-x)); }
__device__ __forceinline__ u16 f2b(float x) {
  unsigned u = __float_as_uint(x);
  return (u16)((u + 0x7FFFu + ((u >> 16) & 1u)) >> 16);
}
__device__ __forceinline__ float b2f(u16 h) { return __uint_as_float(((unsigned)h) << 16); }

// LDS tile: [64 rows][64 bf16] = 128B/row, 8 slots of 16B, XOR-swizzled by row&7
__device__ __forceinline__ u16* ldsp(u16* base, int row, int slot) {
  return base + row * 64 + ((slot ^ (row & 7)) << 3);
}
__device__ __forceinline__ void st8f(u16* base, int row, int slot, float4 a, float4 b) {
  bf16x8 v;
  v[0] = (short)f2b(a.x); v[1] = (short)f2b(a.y); v[2] = (short)f2b(a.z); v[3] = (short)f2b(a.w);
  v[4] = (short)f2b(b.x); v[5] = (short)f2b(b.y); v[6] = (short)f2b(b.z); v[7] = (short)f2b(b.w);
  *(bf16x8*)ldsp(base, row, slot) = v;
}
#define MFMA(a, b, c) __builtin_amdgcn_mfma_f32_16x16x32_bf16(a, b, c, 0, 0, 0)

// ============== zero-fill ==============
__global__ void zero_ws(float4* __restrict__ p, int n4) {
  int i = blockIdx.x * 256 + threadIdx.x;
  int stride = gridDim.x * 256;
  for (; i < n4; i += stride) p[i] = make_float4(0.f, 0.f, 0.f, 0.f);
}

// ============== prep: bf16 TRANSPOSED zero-padded weights ==============
// WpreT[1536][512] (n,k) = W_{z|h|r}[k][n&511]; WzbT/WhbT[512][512] = bottom halves^T;
// UrT[512][512]; WgT[512][1024]; biasp[4][512] fp32
__global__ void prep_pad(const float* __restrict__ Wz, const float* __restrict__ Wh,
                         const float* __restrict__ Wr, const float* __restrict__ Ur,
                         const float* __restrict__ Wg,
                         const float* __restrict__ bz, const float* __restrict__ bh,
                         const float* __restrict__ bur, const float* __restrict__ bg,
                         u16* __restrict__ WpreT, u16* __restrict__ WzbT,
                         u16* __restrict__ WhbT, u16* __restrict__ UrT,
                         u16* __restrict__ WgT, float* __restrict__ biasp) {
  int idx = blockIdx.x * 256 + threadIdx.x;
  if (idx < 1536 * 512) {                         // WpreT
    int n = idx >> 9, k = idx & 511;
    int sel = n >> 9, j = n & 511;
    float v = 0.f;
    if (k < HDIM && j < HDIM) {
      const float* W = (sel == 0) ? Wz : (sel == 1) ? Wh : Wr;
      v = W[k * HDIM + j];
    }
    WpreT[idx] = f2b(v);
    return;
  }
  idx -= 1536 * 512;
  if (idx < 3 * 262144) {                         // WzbT, WhbT, UrT
    int which = idx >> 18; int r = idx & 262143;
    int n = r >> 9, k = r & 511;
    float v = 0.f;
    if (k < HDIM && n < HDIM)
      v = (which == 0) ? Wz[(HDIM + k) * HDIM + n]
        : (which == 1) ? Wh[(HDIM + k) * HDIM + n]
                       : Ur[k * HDIM + n];
    ((which == 0) ? WzbT : (which == 1) ? WhbT : UrT)[r] = f2b(v);
    return;
  }
  idx -= 3 * 262144;
  if (idx < 512 * 1024) {                         // WgT[n][k], k in [0,1024)
    int n = idx >> 10, k = idx & 1023;
    float v = 0.f;
    if (n < HDIM) {
      if (k < HDIM) v = Wg[k * HDIM + n];
      else if (k >= HP && (k - HP) < HDIM) v = Wg[(HDIM + k - HP) * HDIM + n];
    }
    WgT[idx] = f2b(v);
    return;
  }
  idx -= 512 * 1024;
  if (idx < 4 * HP) {                             // biases fp32
    int which = idx >> 9, j = idx & 511;
    float v = 0.f;
    if (j < HDIM)
      v = ((which == 0) ? bz : (which == 1) ? bh : (which == 2) ? bur : bg)[j];
    biasp[idx] = v;
  }
}

// ============== embedding gather -> bf16 x_p[NNODES][512] ==============
__global__ void gather_embed(const int* __restrict__ wid, const float* __restrict__ emb,
                             u16* __restrict__ xp) {
  int gid = blockIdx.x * 256 + threadIdx.x;
  if (gid >= NNODES * 64) return;
  int row = gid >> 6, g = gid & 63;
  int j0 = g * 8;
  const float* er = emb + (size_t)wid[row] * HDIM;
  float f[8] = {0.f, 0.f, 0.f, 0.f, 0.f, 0.f, 0.f, 0.f};
  if (j0 <= 440) {
#pragma unroll
    for (int q = 0; q < 4; ++q) {
      float2 p = *(const float2*)(er + j0 + q * 2);
      f[q * 2] = p.x; f[q * 2 + 1] = p.y;
    }
  } else if (j0 == 448) {
    f[0] = er[448]; f[1] = er[449];
  }
  bf16x8 v;
#pragma unroll
  for (int q = 0; q < 8; ++q) v[q] = (short)f2b(f[q]);
  *(bf16x8*)(xp + (size_t)row * HP + j0) = v;
}

// ============== MFMA GEMM: Xpre = x @ Wpre -> bf16 Xzh, Xr ==============
__global__ __launch_bounds__(256, 2) void mfma_pre(
    const u16* __restrict__ xp, const u16* __restrict__ WpreT,
    u16* __restrict__ Xzh, u16* __restrict__ Xr) {
  __shared__ u16 Al[64 * 64], Bl[64 * 64];
  int tid = threadIdx.x;
  int n0 = blockIdx.x * 64, m0 = blockIdx.y * 64;
  int l = tid & 63, w = tid >> 6, wr = w >> 1, wc = w & 1, lr = l & 15, lq = l >> 4;
  int sr = tid >> 2, skc = tid & 3;
  const u16* abase = xp + (size_t)(m0 + sr) * HP + skc * 16;
  const u16* bbase = WpreT + (size_t)(n0 + sr) * HP + skc * 16;
  f32x4 acc[2][2] = {};
  for (int kt = 0; kt < HP; kt += 64) {
    bf16x8 a0 = ((const bf16x8*)(abase + kt))[0], a1 = ((const bf16x8*)(abase + kt))[1];
    bf16x8 b0 = ((const bf16x8*)(bbase + kt))[0], b1 = ((const bf16x8*)(bbase + kt))[1];
    *(bf16x8*)ldsp(Al, sr, 2 * skc) = a0; *(bf16x8*)ldsp(Al, sr, 2 * skc + 1) = a1;
    *(bf16x8*)ldsp(Bl, sr, 2 * skc) = b0; *(bf16x8*)ldsp(Bl, sr, 2 * skc + 1) = b1;
    __syncthreads();
#pragma unroll
    for (int kk = 0; kk < 64; kk += 32) {
      int slot = (kk >> 3) + lq;
      bf16x8 fa0 = *(bf16x8*)ldsp(Al, wr * 32 + lr, slot);
      bf16x8 fa1 = *(bf16x8*)ldsp(Al, wr * 32 + 16 + lr, slot);
      bf16x8 fb0 = *(bf16x8*)ldsp(Bl, wc * 32 + lr, slot);
      bf16x8 fb1 = *(bf16x8*)ldsp(Bl, wc * 32 + 16 + lr, slot);
      acc[0][0] = MFMA(fa0, fb0, acc[0][0]); acc[0][1] = MFMA(fa0, fb1, acc[0][1]);
      acc[1][0] = MFMA(fa1, fb0, acc[1][0]); acc[1][1] = MFMA(fa1, fb1, acc[1][1]);
    }
    __syncthreads();
  }
#pragma unroll
  for (int fi = 0; fi < 2; ++fi)
#pragma unroll
    for (int fj = 0; fj < 2; ++fj) {
      int colg = n0 + wc * 32 + fj * 16 + lr;
#pragma unroll
      for (int reg = 0; reg < 4; ++reg) {
        int row = m0 + wr * 32 + fi * 16 + lq * 4 + reg;
        u16 o = f2b(acc[fi][fj][reg]);
        if (colg < 1024) Xzh[(size_t)row * 1024 + colg] = o;
        else Xr[(size_t)row * HP + (colg - 1024)] = o;
      }
    }
}

// ============== level 0: m_new = sig(Xz+bz)*tanh(Xh+bh) ==============
__global__ void leaf_lvl0(const int* __restrict__ sched0, const int* __restrict__ src,
                          const u16* __restrict__ Xzh, const float* __restrict__ biasp,
                          float* __restrict__ mup) {
  int gid = blockIdx.x * 256 + threadIdx.x;   // 8192 * 128
  int r = gid >> 7, g = gid & 127;
  int e = sched0[r];
  int se = src[e];
  int col = g * 4;
  ushort4 xz = *(const ushort4*)(Xzh + (size_t)se * 1024 + col);
  ushort4 xh = *(const ushort4*)(Xzh + (size_t)se * 1024 + 512 + col);
  float4 bz = *(const float4*)(biasp + col);
  float4 bh = *(const float4*)(biasp + 512 + col);
  float4 o;
  o.x = sigmoidf_(b2f(xz.x) + bz.x) * tanhf(b2f(xh.x) + bh.x);
  o.y = sigmoidf_(b2f(xz.y) + bz.y) * tanhf(b2f(xh.y) + bh.y);
  o.z = sigmoidf_(b2f(xz.z) + bz.z) * tanhf(b2f(xh.z) + bh.z);
  o.w = sigmoidf_(b2f(xz.w) + bz.w) * tanhf(b2f(xh.w) + bh.w);
  *(float4*)(mup + (size_t)e * HP + col) = o;
}

// ============== up-level GEMM1 (dual): z/mt/m_new ==============
__global__ __launch_bounds__(256, 2) void mfma_lvl1_up(
    const int* __restrict__ schedrow, const int* __restrict__ src,
    const float* __restrict__ node_m, const float* __restrict__ node_rm,
    const u16* __restrict__ Xzh, const u16* __restrict__ WzbT,
    const u16* __restrict__ WhbT, const float* __restrict__ biasp,
    float* __restrict__ mup) {
  __shared__ u16 Asl[64 * 64], Aal[64 * 64], Bzl[64 * 64], Btl[64 * 64];
  __shared__ int e_s[64], se_s[64];
  int tid = threadIdx.x;
  int n0 = blockIdx.x * 64, m0 = blockIdx.y * 64;
  if (tid < 64) { int e = schedrow[m0 + tid]; e_s[tid] = e; se_s[tid] = src[e]; }
  __syncthreads();
  int l = tid & 63, w = tid >> 6, wr = w >> 1, wc = w & 1, lr = l & 15, lq = l >> 4;
  int sr = tid >> 2, skc = tid & 3;
  int se_st = se_s[sr];
  const float* pmb = node_m + (size_t)se_st * HP + skc * 16;
  const float* prb = node_rm + (size_t)se_st * HP + skc * 16;
  const u16* bzb = WzbT + (size_t)(n0 + sr) * HP + skc * 16;
  const u16* btb = WhbT + (size_t)(n0 + sr) * HP + skc * 16;
  f32x4 accZ[2][2] = {}, accT[2][2] = {};
  for (int kt = 0; kt < HP; kt += 64) {
    const float4* pm = (const float4*)(pmb + kt);
    const float4* pr = (const float4*)(prb + kt);
    st8f(Asl, sr, 2 * skc, pm[0], pm[1]); st8f(Asl, sr, 2 * skc + 1, pm[2], pm[3]);
    st8f(Aal, sr, 2 * skc, pr[0], pr[1]); st8f(Aal, sr, 2 * skc + 1, pr[2], pr[3]);
    *(bf16x8*)ldsp(Bzl, sr, 2 * skc) = ((const bf16x8*)(bzb + kt))[0];
    *(bf16x8*)ldsp(Bzl, sr, 2 * skc + 1) = ((const bf16x8*)(bzb + kt))[1];
    *(bf16x8*)ldsp(Btl, sr, 2 * skc) = ((const bf16x8*)(btb + kt))[0];
    *(bf16x8*)ldsp(Btl, sr, 2 * skc + 1) = ((const bf16x8*)(btb + kt))[1];
    __syncthreads();
#pragma unroll
    for (int kk = 0; kk < 64; kk += 32) {
      int slot = (kk >> 3) + lq;
      bf16x8 a0 = *(bf16x8*)ldsp(Asl, wr * 32 + lr, slot);
      bf16x8 a1 = *(bf16x8*)ldsp(Asl, wr * 32 + 16 + lr, slot);
      bf16x8 c0 = *(bf16x8*)ldsp(Aal, wr * 32 + lr, slot);
      bf16x8 c1 = *(bf16x8*)ldsp(Aal, wr * 32 + 16 + lr, slot);
      bf16x8 z0 = *(bf16x8*)ldsp(Bzl, wc * 32 + lr, slot);
      bf16x8 z1 = *(bf16x8*)ldsp(Bzl, wc * 32 + 16 + lr, slot);
      bf16x8 t0 = *(bf16x8*)ldsp(Btl, wc * 32 + lr, slot);
      bf16x8 t1 = *(bf16x8*)ldsp(Btl, wc * 32 + 16 + lr, slot);
      accZ[0][0] = MFMA(a0, z0, accZ[0][0]); accZ[0][1] = MFMA(a0, z1, accZ[0][1]);
      accZ[1][0] = MFMA(a1, z0, accZ[1][0]); accZ[1][1] = MFMA(a1, z1, accZ[1][1]);
      accT[0][0] = MFMA(c0, t0, accT[0][0]); accT[0][1] = MFMA(c0, t1, accT[0][1]);
      accT[1][0] = MFMA(c1, t0, accT[1][0]); accT[1][1] = MFMA(c1, t1, accT[1][1]);
    }
    __syncthreads();
  }
#pragma unroll
  for (int fi = 0; fi < 2; ++fi)
#pragma unroll
    for (int fj = 0; fj < 2; ++fj) {
      int colg = n0 + wc * 32 + fj * 16 + lr;
#pragma unroll
      for (int reg = 0; reg < 4; ++reg) {
        int row = wr * 32 + fi * 16 + lq * 4 + reg;
        int e = e_s[row], se = se_s[row];
        float xz = b2f(Xzh[(size_t)se * 1024 + colg]);
        float xh = b2f(Xzh[(size_t)se * 1024 + 512 + colg]);
        float sv = node_m[(size_t)se * HP + colg];
        float z = sigmoidf_(accZ[fi][fj][reg] + xz + biasp[colg]);
        float t = tanhf(accT[fi][fj][reg] + xh + biasp[512 + colg]);
        mup[(size_t)e * HP + colg] = (1.f - z) * sv + z * t;
      }
    }
}

// ============== down-level GEMM1 (dual, A = differences) ==============
__global__ __launch_bounds__(256, 2) void mfma_lvl1_down(
    const int* __restrict__ schedrow, const int* __restrict__ src,
    const float* __restrict__ node_m, const float* __restrict__ node_rm,
    const float* __restrict__ mup, const float* __restrict__ rmup,
    const u16* __restrict__ Xzh, const u16* __restrict__ WzbT,
    const u16* __restrict__ WhbT, const float* __restrict__ biasp,
    float* __restrict__ dtmp) {
  __shared__ u16 Asl[64 * 64], Aal[64 * 64], Bzl[64 * 64], Btl[64 * 64];
  __shared__ int se_s[64], eu_s[64];
  int tid = threadIdx.x;
  int n0 = blockIdx.x * 64, m0 = blockIdx.y * 64;
  if (tid < 64) { int e = schedrow[m0 + tid]; eu_s[tid] = e - EUP; se_s[tid] = src[e]; }
  __syncthreads();
  int l = tid & 63, w = tid >> 6, wr = w >> 1, wc = w & 1, lr = l & 15, lq = l >> 4;
  int sr = tid >> 2, skc = tid & 3;
  int se_st = se_s[sr], eu_st = eu_s[sr];
  const float* pmb = node_m + (size_t)se_st * HP + skc * 16;
  const float* pub = mup + (size_t)eu_st * HP + skc * 16;
  const float* prb = node_rm + (size_t)se_st * HP + skc * 16;
  const float* pvb = rmup + (size_t)eu_st * HP + skc * 16;
  const u16* bzb = WzbT + (size_t)(n0 + sr) * HP + skc * 16;
  const u16* btb = WhbT + (size_t)(n0 + sr) * HP + skc * 16;
  f32x4 accZ[2][2] = {}, accT[2][2] = {};
  for (int kt = 0; kt < HP; kt += 64) {
    const float4* pm = (const float4*)(pmb + kt);
    const float4* pu = (const float4*)(pub + kt);
    const float4* pr = (const float4*)(prb + kt);
    const float4* pv = (const float4*)(pvb + kt);
    float4 d0, d1, d2, d3;
    d0.x = pm[0].x - pu[0].x; d0.y = pm[0].y - pu[0].y; d0.z = pm[0].z - pu[0].z; d0.w = pm[0].w - pu[0].w;
    d1.x = pm[1].x - pu[1].x; d1.y = pm[1].y - pu[1].y; d1.z = pm[1].z - pu[1].z; d1.w = pm[1].w - pu[1].w;
    d2.x = pm[2].x - pu[2].x; d2.y = pm[2].y - pu[2].y; d2.z = pm[2].z - pu[2].z; d2.w = pm[2].w - pu[2].w;
    d3.x = pm[3].x - pu[3].x; d3.y = pm[3].y - pu[3].y; d3.z = pm[3].z - pu[3].z; d3.w = pm[3].w - pu[3].w;
    st8f(Asl, sr, 2 * skc, d0, d1); st8f(Asl, sr, 2 * skc + 1, d2, d3);
    d0.x = pr[0].x - pv[0].x; d0.y = pr[0].y - pv[0].y; d0.z = pr[0].z - pv[0].z; d0.w = pr[0].w - pv[0].w;
    d1.x = pr[1].x - pv[1].x; d1.y = pr[1].y - pv[1].y; d1.z = pr[1].z - pv[1].z; d1.w = pr[1].w - pv[1].w;
    d2.x = pr[2].x - pv[2].x; d2.y = pr[2].y - pv[2].y; d2.z = pr[2].z - pv[2].z; d2.w = pr[2].w - pv[2].w;
    d3.x = pr[3].x - pv[3].x; d3.y = pr[3].y - pv[3].y; d3.z = pr[3].z - pv[3].z; d3.w = pr[3].w - pv[3].w;
    st8f(Aal, sr, 2 * skc, d0, d1); st8f(Aal, sr, 2 * skc + 1, d2, d3);
    *(bf16x8*)ldsp(Bzl, sr, 2 * skc) = ((const bf16x8*)(bzb + kt))[0];
    *(bf16x8*)ldsp(Bzl, sr, 2 * skc + 1) = ((const bf16x8*)(bzb + kt))[1];
    *(bf16x8*)ldsp(Btl, sr, 2 * skc) = ((const bf16x8*)(btb + kt))[0];
    *(bf16x8*)ldsp(Btl, sr, 2 * skc + 1) = ((const bf16x8*)(btb + kt))[1];
    __syncthreads();
#pragma unroll
    for (int kk = 0; kk < 64; kk += 32) {
      int slot = (kk >> 3) + lq;
      bf16x8 a0 = *(bf16x8*)ldsp(Asl, wr * 32 + lr, slot);
      bf16x8 a1 = *(bf16x8*)ldsp(Asl, wr * 32 + 16 + lr, slot);
      bf16x8 c0 = *(bf16x8*)ldsp(Aal, wr * 32 + lr, slot);
      bf16x8 c1 = *(bf16x8*)ldsp(Aal, wr * 32 + 16 + lr, slot);
      bf16x8 z0 = *(bf16x8*)ldsp(Bzl, wc * 32 + lr, slot);
      bf16x8 z1 = *(bf16x8*)ldsp(Bzl, wc * 32 + 16 + lr, slot);
      bf16x8 t0 = *(bf16x8*)ldsp(Btl, wc * 32 + lr, slot);
      bf16x8 t1 = *(bf16x8*)ldsp(Btl, wc * 32 + 16 + lr, slot);
      accZ[0][0] = MFMA(a0, z0, accZ[0][0]); accZ[0][1] = MFMA(a0, z1, accZ[0][1]);
      accZ[1][0] = MFMA(a1, z0, accZ[1][0]); accZ[1][1] = MFMA(a1, z1, accZ[1][1]);
      accT[0][0] = MFMA(c0, t0, accT[0][0]); accT[0][1] = MFMA(c0, t1, accT[0][1]);
      accT[1][0] = MFMA(c1, t0, accT[1][0]); accT[1][1] = MFMA(c1, t1, accT[1][1]);
    }
    __syncthreads();
  }
#pragma unroll
  for (int fi = 0; fi < 2; ++fi)
#pragma unroll
    for (int fj = 0; fj < 2; ++fj) {
      int colg = n0 + wc * 32 + fj * 16 + lr;
#pragma unroll
      for (int reg = 0; reg < 4; ++reg) {
        int row = wr * 32 + fi * 16 + lq * 4 + reg;
        int se = se_s[row], eu = eu_s[row];
        float xz = b2f(Xzh[(size_t)se * 1024 + colg]);
        float xh = b2f(Xzh[(size_t)se * 1024 + 512 + colg]);
        float sv = node_m[(size_t)se * HP + colg] - mup[(size_t)eu * HP + colg];
        float z = sigmoidf_(accZ[fi][fj][reg] + xz + biasp[colg]);
        float t = tanhf(accT[fi][fj][reg] + xh + biasp[512 + colg]);
        dtmp[(size_t)(m0 + row) * HP + colg] = (1.f - z) * sv + z * t;
      }
    }
}

// ============== up-level GEMM2: r, rmup, pair-store node accumulators ==============
__global__ __launch_bounds__(256, 2) void mfma_lvl2_up(
    const int* __restrict__ schedrow, const int* __restrict__ dst,
    const float* __restrict__ mup, float* __restrict__ rmup,
    float* __restrict__ node_m, float* __restrict__ node_rm,
    const u16* __restrict__ Xr, const u16* __restrict__ UrT,
    const float* __restrict__ biasp) {
  __shared__ u16 Al[64 * 64], Bl[64 * 64];
  __shared__ int e_s[64], de_s[64];
  int tid = threadIdx.x;
  int n0 = blockIdx.x * 64, m0 = blockIdx.y * 64;
  if (tid < 64) { int e = schedrow[m0 + tid]; e_s[tid] = e; de_s[tid] = dst[e]; }
  __syncthreads();
  int l = tid & 63, w = tid >> 6, wr = w >> 1, wc = w & 1, lr = l & 15, lq = l >> 4;
  int sr = tid >> 2, skc = tid & 3;
  const float* ab = mup + (size_t)e_s[sr] * HP + skc * 16;
  const u16* bb = UrT + (size_t)(n0 + sr) * HP + skc * 16;
  f32x4 acc[2][2] = {};
  for (int kt = 0; kt < HP; kt += 64) {
    const float4* pa = (const float4*)(ab + kt);
    st8f(Al, sr, 2 * skc, pa[0], pa[1]); st8f(Al, sr, 2 * skc + 1, pa[2], pa[3]);
    *(bf16x8*)ldsp(Bl, sr, 2 * skc) = ((const bf16x8*)(bb + kt))[0];
    *(bf16x8*)ldsp(Bl, sr, 2 * skc + 1) = ((const bf16x8*)(bb + kt))[1];
    __syncthreads();
#pragma unroll
    for (int kk = 0; kk < 64; kk += 32) {
      int slot = (kk >> 3) + lq;
      bf16x8 fa0 = *(bf16x8*)ldsp(Al, wr * 32 + lr, slot);
      bf16x8 fa1 = *(bf16x8*)ldsp(Al, wr * 32 + 16 + lr, slot);
      bf16x8 fb0 = *(bf16x8*)ldsp(Bl, wc * 32 + lr, slot);
      bf16x8 fb1 = *(bf16x8*)ldsp(Bl, wc * 32 + 16 + lr, slot);
      acc[0][0] = MFMA(fa0, fb0, acc[0][0]); acc[0][1] = MFMA(fa0, fb1, acc[0][1]);
      acc[1][0] = MFMA(fa1, fb0, acc[1][0]); acc[1][1] = MFMA(fa1, fb1, acc[1][1]);
    }
    __syncthreads();
  }
#pragma unroll
  for (int fi = 0; fi < 2; ++fi)
#pragma unroll
    for (int fj = 0; fj < 2; ++fj) {
      int colg = n0 + wc * 32 + fj * 16 + lr;
      int rowbase = wr * 32 + fi * 16 + lq * 4;
      float mv[4], rmv[4];
#pragma unroll
      for (int reg = 0; reg < 4; ++reg) {
        int row = rowbase + reg;
        int e = e_s[row], de = de_s[row];
        mv[reg] = mup[(size_t)e * HP + colg];
        float r = sigmoidf_(acc[fi][fj][reg] + b2f(Xr[(size_t)de * HP + colg]) + biasp[1024 + colg]);
        rmv[reg] = r * mv[reg];
        rmup[(size_t)e * HP + colg] = rmv[reg];
      }
      int de0 = de_s[rowbase], de2 = de_s[rowbase + 2];
      node_m[(size_t)de0 * HP + colg] = mv[0] + mv[1];
      node_rm[(size_t)de0 * HP + colg] = rmv[0] + rmv[1];
      node_m[(size_t)de2 * HP + colg] = mv[2] + mv[3];
      node_rm[(size_t)de2 * HP + colg] = rmv[2] + rmv[3];
    }
}

// ============== down-level GEMM2: r; node accumulators += ==============
__global__ __launch_bounds__(256, 2) void mfma_lvl2_down(
    const int* __restrict__ schedrow, const int* __restrict__ dst,
    const float* __restrict__ dtmp,
    float* __restrict__ node_m, float* __restrict__ node_rm,
    const u16* __restrict__ Xr, const u16* __restrict__ UrT,
    const float* __restrict__ biasp) {
  __shared__ u16 Al[64 * 64], Bl[64 * 64];
  __shared__ int de_s[64];
  int tid = threadIdx.x;
  int n0 = blockIdx.x * 64, m0 = blockIdx.y * 64;
  if (tid < 64) de_s[tid] = dst[schedrow[m0 + tid]];
  __syncthreads();
  int l = tid & 63, w = tid >> 6, wr = w >> 1, wc = w & 1, lr = l & 15, lq = l >> 4;
  int sr = tid >> 2, skc = tid & 3;
  const float* ab = dtmp + (size_t)(m0 + sr) * HP + skc * 16;
  const u16* bb = UrT + (size_t)(n0 + sr) * HP + skc * 16;
  f32x4 acc[2][2] = {};
  for (int kt = 0; kt < HP; kt += 64) {
    const float4* pa = (const float4*)(ab + kt);
    st8f(Al, sr, 2 * skc, pa[0], pa[1]); st8f(Al, sr, 2 * skc + 1, pa[2], pa[3]);
    *(bf16x8*)ldsp(Bl, sr, 2 * skc) = ((const bf16x8*)(bb + kt))[0];
    *(bf16x8*)ldsp(Bl, sr, 2 * skc + 1) = ((const bf16x8*)(bb + kt))[1];
    __syncthreads();
#pragma unroll
    for (int kk = 0; kk < 64; kk += 32) {
      int slot = (kk >> 3) + lq;
      bf16x8 fa0 = *(bf16x8*)ldsp(Al, wr * 32 + lr, slot);
      bf16x8 fa1 = *(bf16x8*)ldsp(Al, wr * 32 + 16 + lr, slot);
      bf16x8 fb0 = *(bf16x8*)ldsp(Bl, wc * 32 + lr, slot);
      bf16x8 fb1 = *(bf16x8*)ldsp(Bl, wc * 32 + 16 + lr, slot);
      acc[0][0] = MFMA(fa0, fb0, acc[0][0]); acc[0][1] = MFMA(fa0, fb1, acc[0][1]);
      acc[1][0] = MFMA(fa1, fb0, acc[1][0]); acc[1][1] = MFMA(fa1, fb1, acc[1][1]);
    }
    __syncthreads();
  }
#pragma unroll
  for (int fi = 0; fi < 2; ++fi)
#pragma unroll
    for (int fj = 0; fj < 2; ++fj) {
      int colg = n0 + wc * 32 + fj * 16 + lr;
#pragma unroll
      for (int reg = 0; reg < 4; ++reg) {
        int row = wr * 32 + fi * 16 + lq * 4 + reg;
        int de = de_s[row];
        float mv = dtmp[(size_t)(m0 + row) * HP + colg];
        float r = sigmoidf_(acc[fi][fj][reg] + b2f(Xr[(size_t)de * HP + colg]) + biasp[1024 + colg]);
        node_m[(size_t)de * HP + colg] += mv;
        node_rm[(size_t)de * HP + colg] += r * mv;
      }
    }
}

// ============== final GEMM: h = relu([x, node_m] @ Wg + bg) ==============
__global__ __launch_bounds__(256, 2) void mfma_final(
    const u16* __restrict__ xp, const float* __restrict__ node_m,
    const u16* __restrict__ WgT, const float* __restrict__ biasp,
    float* __restrict__ out) {
  __shared__ u16 Al[64 * 64], Bl[64 * 64];
  int tid = threadIdx.x;
  int n0 = blockIdx.x * 64, m0 = blockIdx.y * 64;
  int l = tid & 63, w = tid >> 6, wr = w >> 1, wc = w & 1, lr = l & 15, lq = l >> 4;
  int sr = tid >> 2, skc = tid & 3;
  const u16* axb = xp + (size_t)(m0 + sr) * HP + skc * 16;
  const float* anb = node_m + (size_t)(m0 + sr) * HP + skc * 16;
  const u16* bb = WgT + (size_t)(n0 + sr) * 1024 + skc * 16;
  f32x4 acc[2][2] = {};
  for (int kt = 0; kt < 1024; kt += 64) {
    if (kt < HP) {
      *(bf16x8*)ldsp(Al, sr, 2 * skc) = ((const bf16x8*)(axb + kt))[0];
      *(bf16x8*)ldsp(Al, sr, 2 * skc + 1) = ((const bf16x8*)(axb + kt))[1];
    } else {
      const float4* pa = (const float4*)(anb + (kt - HP));
      st8f(Al, sr, 2 * skc, pa[0], pa[1]); st8f(Al, sr, 2 * skc + 1, pa[2], pa[3]);
    }
    *(bf16x8*)ldsp(Bl, sr, 2 * skc) = ((const bf16x8*)(bb + kt))[0];
    *(bf16x8*)ldsp(Bl, sr, 2 * skc + 1) = ((const bf16x8*)(bb + kt))[1];
    __syncthreads();
#pragma unroll
    for (int kk = 0; kk < 64; kk += 32) {
      int slot = (kk >> 3) + lq;
      bf16x8 fa0 = *(bf16x8*)ldsp(Al, wr * 32 + lr, slot);
      bf16x8 fa1 = *(bf16x8*)ldsp(Al, wr * 32 + 16 + lr, slot);
      bf16x8 fb0 = *(bf16x8*)ldsp(Bl, wc * 32 + lr, slot);
      bf16x8 fb1 = *(bf16x8*)ldsp(Bl, wc * 32 + 16 + lr, slot);
      acc[0][0] = MFMA(fa0, fb0, acc[0][0]); acc[0][1] = MFMA(fa0, fb1, acc[0][1]);
      acc[1][0] = MFMA(fa1, fb0, acc[1][0]); acc[1][1] = MFMA(fa1, fb1, acc[1][1]);
    }
    __syncthreads();
  }
#pragma unroll
  for (int fi = 0; fi < 2; ++fi)
#pragma unroll
    for (int fj = 0; fj < 2; ++fj) {
      int colg = n0 + wc * 32 + fj * 16 + lr;
      if (colg >= HDIM) continue;
#pragma unroll
      for (int reg = 0; reg < 4; ++reg) {
        int row = m0 + wr * 32 + fi * 16 + lq * 4 + reg;
        float v = acc[fi][fj][reg] + biasp[1536 + colg];
        out[(size_t)row * HDIM + colg] = v > 0.f ? v : 0.f;
      }
    }
}

// ====================== host launcher ======================
extern "C" void kernel_launch(void* const* d_in, const int* in_sizes, int n_in,
                              void* d_out, int out_size, void* d_ws, size_t ws_size,
                              hipStream_t stream) {
  const int* wid = (const int*)d_in[0];
  const int* src = (const int*)d_in[1];
  const int* dst = (const int*)d_in[2];
  const int* sched = (const int*)d_in[4];
  const float* emb = (const float*)d_in[5];
  const float* Wz = (const float*)d_in[6];
  const float* bz = (const float*)d_in[7];
  const float* Wr = (const float*)d_in[8];
  const float* Ur = (const float*)d_in[9];
  const float* bur = (const float*)d_in[10];
  const float* Wh = (const float*)d_in[11];
  const float* bh = (const float*)d_in[12];
  const float* Wg = (const float*)d_in[13];
  const float* bg = (const float*)d_in[14];
  float* out = (float*)d_out;
  float* ws = (float*)d_ws;

  // ---- workspace layout (fp32 units), total ~220 MB ----
  size_t o = 0;
  u16* x_p = (u16*)(ws + o);   o += (size_t)NNODES * HP / 2;       // bf16
  u16* Xzh = (u16*)(ws + o);   o += (size_t)NNODES * 1024 / 2;     // bf16
  u16* Xr = (u16*)(ws + o);    o += (size_t)NNODES * HP / 2;       // bf16
  float* node_m = ws + o;      o += (size_t)NNODES * HP;
  float* node_rm = ws + o;     o += (size_t)NNODES * HP;
  float* mup = ws + o;         o += (size_t)EUP * HP;
  float* rmup = ws + o;        o += (size_t)EUP * HP;
  float* dtmp = ws + o;        o += (size_t)LMAX * HP;
  u16* WpreT = (u16*)(ws + o); o += (size_t)1536 * HP / 2;
  u16* WzbT = (u16*)(ws + o);  o += (size_t)HP * HP / 2;
  u16* WhbT = (u16*)(ws + o);  o += (size_t)HP * HP / 2;
  u16* UrT = (u16*)(ws + o);   o += (size_t)HP * HP / 2;
  u16* WgT = (u16*)(ws + o);   o += (size_t)HP * 1024 / 2;
  float* biasp = ws + o;       o += (size_t)4 * HP;
  if (ws_size < o * sizeof(float)) return;  // diagnostic guard

  // zero node_m + node_rm (contiguous)
  size_t zf = (size_t)2 * NNODES * HP;
  zero_ws<<<2048, 256, 0, stream>>>((float4*)node_m, (int)(zf / 4));

  int prep_elems = 1536 * 512 + 3 * 262144 + 512 * 1024 + 4 * HP;
  prep_pad<<<(prep_elems + 255) / 256, 256, 0, stream>>>(
      Wz, Wh, Wr, Ur, Wg, bz, bh, bur, bg, WpreT, WzbT, WhbT, UrT, WgT, biasp);

  gather_embed<<<(NNODES * 64 + 255) / 256, 256, 0, stream>>>(wid, emb, x_p);

  mfma_pre<<<dim3(1536 / 64, NNODES / 64), 256, 0, stream>>>(x_p, WpreT, Xzh, Xr);

  for (int lvl = 0; lvl < NLVL; ++lvl) {
    int L = (lvl < 6) ? (LMAX >> lvl) : (256 << (lvl - 6));
    const int* schedrow = sched + (size_t)lvl * LMAX;
    if (lvl == 0) {
      leaf_lvl0<<<4096, 256, 0, stream>>>(schedrow, src, Xzh, biasp, mup);
    } else if (lvl < 6) {
      mfma_lvl1_up<<<dim3(8, L / 64), 256, 0, stream>>>(
          schedrow, src, node_m, node_rm, Xzh, WzbT, WhbT, biasp, mup);
    } else {
      mfma_lvl1_down<<<dim3(8, L / 64), 256, 0, stream>>>(
          schedrow, src, node_m, node_rm, mup, rmup, Xzh, WzbT, WhbT, biasp, dtmp);
    }
    if (lvl < 6) {
      mfma_lvl2_up<<<dim3(8, L / 64), 256, 0, stream>>>(
          schedrow, dst, mup, rmup, node_m, node_rm, Xr, UrT, biasp);
    } else {
      mfma_lvl2_down<<<dim3(8, L / 64), 256, 0, stream>>>(
          schedrow, dst, dtmp, node_m, node_rm, Xr, UrT, biasp);
    }
  }

  mfma_final<<<dim3(8, NNODES / 64), 256, 0, stream>>>(x_p, node_m, WgT, biasp, out);
}

// Round 4
// 624.073 us; speedup vs baseline: 3.2059x; 1.2479x over previous
//
#include <hip/hip_runtime.h>
#include <math.h>

// ---------------- problem constants ----------------
#define NTREES 128
#define NPT 127
#define NNODES (NTREES*NPT)      // 16256
#define EUP (NTREES*(NPT-1))     // 16128
#define HDIM 450
#define HP 512
#define LMAX 8192
#define NLVL 12

typedef unsigned short u16;
typedef __attribute__((ext_vector_type(8))) short bf16x8;
typedef __attribute__((ext_vector_type(4))) float f32x4;

__device__ __forceinline__ float sigmoidf_(float x) { return 1.f / (1.f + expf(-x)); }
__device__ __forceinline__ u16 f2b(float x) {
  unsigned u = __float_as_uint(x);
  return (u16)((u + 0x7FFFu + ((u >> 16) & 1u)) >> 16);
}
__device__ __forceinline__ float b2f(u16 h) { return __uint_as_float(((unsigned)h) << 16); }
// elementwise bf16 difference computed in fp32
__device__ __forceinline__ bf16x8 sub8(bf16x8 a, bf16x8 b) {
  bf16x8 r;
#pragma unroll
  for (int i = 0; i < 8; ++i) r[i] = (short)f2b(b2f((u16)a[i]) - b2f((u16)b[i]));
  return r;
}

// LDS tile: [64 rows][64 bf16] = 128B/row, 8 slots of 16B, XOR-swizzled by row&7
__device__ __forceinline__ u16* ldsp(u16* base, int row, int slot) {
  return base + row * 64 + ((slot ^ (row & 7)) << 3);
}
#define MFMA(a, b, c) __builtin_amdgcn_mfma_f32_16x16x32_bf16(a, b, c, 0, 0, 0)

// ============== zero-fill ==============
__global__ void zero_ws(float4* __restrict__ p, int n4) {
  int i = blockIdx.x * 256 + threadIdx.x;
  int stride = gridDim.x * 256;
  for (; i < n4; i += stride) p[i] = make_float4(0.f, 0.f, 0.f, 0.f);
}

// ============== prep: bf16 TRANSPOSED zero-padded weights ==============
__global__ void prep_pad(const float* __restrict__ Wz, const float* __restrict__ Wh,
                         const float* __restrict__ Wr, const float* __restrict__ Ur,
                         const float* __restrict__ Wg,
                         const float* __restrict__ bz, const float* __restrict__ bh,
                         const float* __restrict__ bur, const float* __restrict__ bg,
                         u16* __restrict__ WpreT, u16* __restrict__ WzbT,
                         u16* __restrict__ WhbT, u16* __restrict__ UrT,
                         u16* __restrict__ WgT, float* __restrict__ biasp) {
  int idx = blockIdx.x * 256 + threadIdx.x;
  if (idx < 1536 * 512) {                         // WpreT[n][k]
    int n = idx >> 9, k = idx & 511;
    int sel = n >> 9, j = n & 511;
    float v = 0.f;
    if (k < HDIM && j < HDIM) {
      const float* W = (sel == 0) ? Wz : (sel == 1) ? Wh : Wr;
      v = W[k * HDIM + j];
    }
    WpreT[idx] = f2b(v);
    return;
  }
  idx -= 1536 * 512;
  if (idx < 3 * 262144) {                         // WzbT, WhbT, UrT
    int which = idx >> 18; int r = idx & 262143;
    int n = r >> 9, k = r & 511;
    float v = 0.f;
    if (k < HDIM && n < HDIM)
      v = (which == 0) ? Wz[(HDIM + k) * HDIM + n]
        : (which == 1) ? Wh[(HDIM + k) * HDIM + n]
                       : Ur[k * HDIM + n];
    ((which == 0) ? WzbT : (which == 1) ? WhbT : UrT)[r] = f2b(v);
    return;
  }
  idx -= 3 * 262144;
  if (idx < 512 * 1024) {                         // WgT[n][k], k in [0,1024)
    int n = idx >> 10, k = idx & 1023;
    float v = 0.f;
    if (n < HDIM) {
      if (k < HDIM) v = Wg[k * HDIM + n];
      else if (k >= HP && (k - HP) < HDIM) v = Wg[(HDIM + k - HP) * HDIM + n];
    }
    WgT[idx] = f2b(v);
    return;
  }
  idx -= 512 * 1024;
  if (idx < 4 * HP) {                             // biases fp32
    int which = idx >> 9, j = idx & 511;
    float v = 0.f;
    if (j < HDIM)
      v = ((which == 0) ? bz : (which == 1) ? bh : (which == 2) ? bur : bg)[j];
    biasp[idx] = v;
  }
}

// ============== embedding gather -> bf16 x_p[NNODES][512] ==============
__global__ void gather_embed(const int* __restrict__ wid, const float* __restrict__ emb,
                             u16* __restrict__ xp) {
  int gid = blockIdx.x * 256 + threadIdx.x;
  if (gid >= NNODES * 64) return;
  int row = gid >> 6, g = gid & 63;
  int j0 = g * 8;
  const float* er = emb + (size_t)wid[row] * HDIM;
  float f[8] = {0.f, 0.f, 0.f, 0.f, 0.f, 0.f, 0.f, 0.f};
  if (j0 <= 440) {
#pragma unroll
    for (int q = 0; q < 4; ++q) {
      float2 p = *(const float2*)(er + j0 + q * 2);
      f[q * 2] = p.x; f[q * 2 + 1] = p.y;
    }
  } else if (j0 == 448) {
    f[0] = er[448]; f[1] = er[449];
  }
  bf16x8 v;
#pragma unroll
  for (int q = 0; q < 8; ++q) v[q] = (short)f2b(f[q]);
  *(bf16x8*)(xp + (size_t)row * HP + j0) = v;
}

// ============== MFMA GEMM: Xpre = x @ Wpre -> bf16 Xzh, Xr ==============
__global__ __launch_bounds__(256, 4) void mfma_pre(
    const u16* __restrict__ xp, const u16* __restrict__ WpreT,
    u16* __restrict__ Xzh, u16* __restrict__ Xr) {
  __shared__ u16 Al[64 * 64], Bl[64 * 64];
  int tid = threadIdx.x;
  int n0 = blockIdx.x * 64, m0 = blockIdx.y * 64;
  int l = tid & 63, w = tid >> 6, wr = w >> 1, wc = w & 1, lr = l & 15, lq = l >> 4;
  int sr = tid >> 2, skc = tid & 3;
  const u16* abase = xp + (size_t)(m0 + sr) * HP + skc * 16;
  const u16* bbase = WpreT + (size_t)(n0 + sr) * HP + skc * 16;
  f32x4 acc[2][2] = {};
  for (int kt = 0; kt < HP; kt += 64) {
    *(bf16x8*)ldsp(Al, sr, 2 * skc) = ((const bf16x8*)(abase + kt))[0];
    *(bf16x8*)ldsp(Al, sr, 2 * skc + 1) = ((const bf16x8*)(abase + kt))[1];
    *(bf16x8*)ldsp(Bl, sr, 2 * skc) = ((const bf16x8*)(bbase + kt))[0];
    *(bf16x8*)ldsp(Bl, sr, 2 * skc + 1) = ((const bf16x8*)(bbase + kt))[1];
    __syncthreads();
#pragma unroll
    for (int kk = 0; kk < 64; kk += 32) {
      int slot = (kk >> 3) + lq;
      bf16x8 fa0 = *(bf16x8*)ldsp(Al, wr * 32 + lr, slot);
      bf16x8 fa1 = *(bf16x8*)ldsp(Al, wr * 32 + 16 + lr, slot);
      bf16x8 fb0 = *(bf16x8*)ldsp(Bl, wc * 32 + lr, slot);
      bf16x8 fb1 = *(bf16x8*)ldsp(Bl, wc * 32 + 16 + lr, slot);
      acc[0][0] = MFMA(fa0, fb0, acc[0][0]); acc[0][1] = MFMA(fa0, fb1, acc[0][1]);
      acc[1][0] = MFMA(fa1, fb0, acc[1][0]); acc[1][1] = MFMA(fa1, fb1, acc[1][1]);
    }
    __syncthreads();
  }
#pragma unroll
  for (int fi = 0; fi < 2; ++fi)
#pragma unroll
    for (int fj = 0; fj < 2; ++fj) {
      int colg = n0 + wc * 32 + fj * 16 + lr;
#pragma unroll
      for (int reg = 0; reg < 4; ++reg) {
        int row = m0 + wr * 32 + fi * 16 + lq * 4 + reg;
        u16 o = f2b(acc[fi][fj][reg]);
        if (colg < 1024) Xzh[(size_t)row * 1024 + colg] = o;
        else Xr[(size_t)row * HP + (colg - 1024)] = o;
      }
    }
}

// ============== level 0: m_new = sig(Xz+bz)*tanh(Xh+bh) -> bf16 mup ==============
__global__ void leaf_lvl0(const int* __restrict__ sched0, const int* __restrict__ src,
                          const u16* __restrict__ Xzh, const float* __restrict__ biasp,
                          u16* __restrict__ mup) {
  int gid = blockIdx.x * 256 + threadIdx.x;   // 8192 * 128
  int r = gid >> 7, g = gid & 127;
  int e = sched0[r];
  int se = src[e];
  int col = g * 4;
  ushort4 xz = *(const ushort4*)(Xzh + (size_t)se * 1024 + col);
  ushort4 xh = *(const ushort4*)(Xzh + (size_t)se * 1024 + 512 + col);
  float4 bz = *(const float4*)(biasp + col);
  float4 bh = *(const float4*)(biasp + 512 + col);
  ushort4 o;
  o.x = f2b(sigmoidf_(b2f(xz.x) + bz.x) * tanhf(b2f(xh.x) + bh.x));
  o.y = f2b(sigmoidf_(b2f(xz.y) + bz.y) * tanhf(b2f(xh.y) + bh.y));
  o.z = f2b(sigmoidf_(b2f(xz.z) + bz.z) * tanhf(b2f(xh.z) + bh.z));
  o.w = f2b(sigmoidf_(b2f(xz.w) + bz.w) * tanhf(b2f(xh.w) + bh.w));
  *(ushort4*)(mup + (size_t)e * HP + col) = o;
}

// ============== up-level GEMM1 (dual): z/mt/m_new ==============
__global__ __launch_bounds__(256, 4) void mfma_lvl1_up(
    const int* __restrict__ schedrow, const int* __restrict__ src,
    const u16* __restrict__ node_m, const u16* __restrict__ node_rm,
    const u16* __restrict__ Xzh, const u16* __restrict__ WzbT,
    const u16* __restrict__ WhbT, const float* __restrict__ biasp,
    u16* __restrict__ mup) {
  __shared__ u16 Asl[64 * 64], Aal[64 * 64], Bzl[64 * 64], Btl[64 * 64];
  __shared__ int e_s[64], se_s[64];
  int tid = threadIdx.x;
  int n0 = blockIdx.x * 64, m0 = blockIdx.y * 64;
  if (tid < 64) { int e = schedrow[m0 + tid]; e_s[tid] = e; se_s[tid] = src[e]; }
  __syncthreads();
  int l = tid & 63, w = tid >> 6, wr = w >> 1, wc = w & 1, lr = l & 15, lq = l >> 4;
  int sr = tid >> 2, skc = tid & 3;
  int se_st = se_s[sr];
  const u16* pmb = node_m + (size_t)se_st * HP + skc * 16;
  const u16* prb = node_rm + (size_t)se_st * HP + skc * 16;
  const u16* bzb = WzbT + (size_t)(n0 + sr) * HP + skc * 16;
  const u16* btb = WhbT + (size_t)(n0 + sr) * HP + skc * 16;
  f32x4 accZ[2][2] = {}, accT[2][2] = {};
  for (int kt = 0; kt < HP; kt += 64) {
    *(bf16x8*)ldsp(Asl, sr, 2 * skc) = ((const bf16x8*)(pmb + kt))[0];
    *(bf16x8*)ldsp(Asl, sr, 2 * skc + 1) = ((const bf16x8*)(pmb + kt))[1];
    *(bf16x8*)ldsp(Aal, sr, 2 * skc) = ((const bf16x8*)(prb + kt))[0];
    *(bf16x8*)ldsp(Aal, sr, 2 * skc + 1) = ((const bf16x8*)(prb + kt))[1];
    *(bf16x8*)ldsp(Bzl, sr, 2 * skc) = ((const bf16x8*)(bzb + kt))[0];
    *(bf16x8*)ldsp(Bzl, sr, 2 * skc + 1) = ((const bf16x8*)(bzb + kt))[1];
    *(bf16x8*)ldsp(Btl, sr, 2 * skc) = ((const bf16x8*)(btb + kt))[0];
    *(bf16x8*)ldsp(Btl, sr, 2 * skc + 1) = ((const bf16x8*)(btb + kt))[1];
    __syncthreads();
#pragma unroll
    for (int kk = 0; kk < 64; kk += 32) {
      int slot = (kk >> 3) + lq;
      bf16x8 a0 = *(bf16x8*)ldsp(Asl, wr * 32 + lr, slot);
      bf16x8 a1 = *(bf16x8*)ldsp(Asl, wr * 32 + 16 + lr, slot);
      bf16x8 c0 = *(bf16x8*)ldsp(Aal, wr * 32 + lr, slot);
      bf16x8 c1 = *(bf16x8*)ldsp(Aal, wr * 32 + 16 + lr, slot);
      bf16x8 z0 = *(bf16x8*)ldsp(Bzl, wc * 32 + lr, slot);
      bf16x8 z1 = *(bf16x8*)ldsp(Bzl, wc * 32 + 16 + lr, slot);
      bf16x8 t0 = *(bf16x8*)ldsp(Btl, wc * 32 + lr, slot);
      bf16x8 t1 = *(bf16x8*)ldsp(Btl, wc * 32 + 16 + lr, slot);
      accZ[0][0] = MFMA(a0, z0, accZ[0][0]); accZ[0][1] = MFMA(a0, z1, accZ[0][1]);
      accZ[1][0] = MFMA(a1, z0, accZ[1][0]); accZ[1][1] = MFMA(a1, z1, accZ[1][1]);
      accT[0][0] = MFMA(c0, t0, accT[0][0]); accT[0][1] = MFMA(c0, t1, accT[0][1]);
      accT[1][0] = MFMA(c1, t0, accT[1][0]); accT[1][1] = MFMA(c1, t1, accT[1][1]);
    }
    __syncthreads();
  }
#pragma unroll
  for (int fi = 0; fi < 2; ++fi)
#pragma unroll
    for (int fj = 0; fj < 2; ++fj) {
      int colg = n0 + wc * 32 + fj * 16 + lr;
#pragma unroll
      for (int reg = 0; reg < 4; ++reg) {
        int row = wr * 32 + fi * 16 + lq * 4 + reg;
        int e = e_s[row], se = se_s[row];
        float xz = b2f(Xzh[(size_t)se * 1024 + colg]);
        float xh = b2f(Xzh[(size_t)se * 1024 + 512 + colg]);
        float sv = b2f(node_m[(size_t)se * HP + colg]);
        float z = sigmoidf_(accZ[fi][fj][reg] + xz + biasp[colg]);
        float t = tanhf(accT[fi][fj][reg] + xh + biasp[512 + colg]);
        mup[(size_t)e * HP + colg] = f2b((1.f - z) * sv + z * t);
      }
    }
}

// ============== down-level GEMM1 (dual, A = differences) ==============
__global__ __launch_bounds__(256, 4) void mfma_lvl1_down(
    const int* __restrict__ schedrow, const int* __restrict__ src,
    const u16* __restrict__ node_m, const u16* __restrict__ node_rm,
    const u16* __restrict__ mup, const u16* __restrict__ rmup,
    const u16* __restrict__ Xzh, const u16* __restrict__ WzbT,
    const u16* __restrict__ WhbT, const float* __restrict__ biasp,
    u16* __restrict__ dtmp) {
  __shared__ u16 Asl[64 * 64], Aal[64 * 64], Bzl[64 * 64], Btl[64 * 64];
  __shared__ int se_s[64], eu_s[64];
  int tid = threadIdx.x;
  int n0 = blockIdx.x * 64, m0 = blockIdx.y * 64;
  if (tid < 64) { int e = schedrow[m0 + tid]; eu_s[tid] = e - EUP; se_s[tid] = src[e]; }
  __syncthreads();
  int l = tid & 63, w = tid >> 6, wr = w >> 1, wc = w & 1, lr = l & 15, lq = l >> 4;
  int sr = tid >> 2, skc = tid & 3;
  int se_st = se_s[sr], eu_st = eu_s[sr];
  const u16* pmb = node_m + (size_t)se_st * HP + skc * 16;
  const u16* pub = mup + (size_t)eu_st * HP + skc * 16;
  const u16* prb = node_rm + (size_t)se_st * HP + skc * 16;
  const u16* pvb = rmup + (size_t)eu_st * HP + skc * 16;
  const u16* bzb = WzbT + (size_t)(n0 + sr) * HP + skc * 16;
  const u16* btb = WhbT + (size_t)(n0 + sr) * HP + skc * 16;
  f32x4 accZ[2][2] = {}, accT[2][2] = {};
  for (int kt = 0; kt < HP; kt += 64) {
    *(bf16x8*)ldsp(Asl, sr, 2 * skc) = sub8(((const bf16x8*)(pmb + kt))[0], ((const bf16x8*)(pub + kt))[0]);
    *(bf16x8*)ldsp(Asl, sr, 2 * skc + 1) = sub8(((const bf16x8*)(pmb + kt))[1], ((const bf16x8*)(pub + kt))[1]);
    *(bf16x8*)ldsp(Aal, sr, 2 * skc) = sub8(((const bf16x8*)(prb + kt))[0], ((const bf16x8*)(pvb + kt))[0]);
    *(bf16x8*)ldsp(Aal, sr, 2 * skc + 1) = sub8(((const bf16x8*)(prb + kt))[1], ((const bf16x8*)(pvb + kt))[1]);
    *(bf16x8*)ldsp(Bzl, sr, 2 * skc) = ((const bf16x8*)(bzb + kt))[0];
    *(bf16x8*)ldsp(Bzl, sr, 2 * skc + 1) = ((const bf16x8*)(bzb + kt))[1];
    *(bf16x8*)ldsp(Btl, sr, 2 * skc) = ((const bf16x8*)(btb + kt))[0];
    *(bf16x8*)ldsp(Btl, sr, 2 * skc + 1) = ((const bf16x8*)(btb + kt))[1];
    __syncthreads();
#pragma unroll
    for (int kk = 0; kk < 64; kk += 32) {
      int slot = (kk >> 3) + lq;
      bf16x8 a0 = *(bf16x8*)ldsp(Asl, wr * 32 + lr, slot);
      bf16x8 a1 = *(bf16x8*)ldsp(Asl, wr * 32 + 16 + lr, slot);
      bf16x8 c0 = *(bf16x8*)ldsp(Aal, wr * 32 + lr, slot);
      bf16x8 c1 = *(bf16x8*)ldsp(Aal, wr * 32 + 16 + lr, slot);
      bf16x8 z0 = *(bf16x8*)ldsp(Bzl, wc * 32 + lr, slot);
      bf16x8 z1 = *(bf16x8*)ldsp(Bzl, wc * 32 + 16 + lr, slot);
      bf16x8 t0 = *(bf16x8*)ldsp(Btl, wc * 32 + lr, slot);
      bf16x8 t1 = *(bf16x8*)ldsp(Btl, wc * 32 + 16 + lr, slot);
      accZ[0][0] = MFMA(a0, z0, accZ[0][0]); accZ[0][1] = MFMA(a0, z1, accZ[0][1]);
      accZ[1][0] = MFMA(a1, z0, accZ[1][0]); accZ[1][1] = MFMA(a1, z1, accZ[1][1]);
      accT[0][0] = MFMA(c0, t0, accT[0][0]); accT[0][1] = MFMA(c0, t1, accT[0][1]);
      accT[1][0] = MFMA(c1, t0, accT[1][0]); accT[1][1] = MFMA(c1, t1, accT[1][1]);
    }
    __syncthreads();
  }
#pragma unroll
  for (int fi = 0; fi < 2; ++fi)
#pragma unroll
    for (int fj = 0; fj < 2; ++fj) {
      int colg = n0 + wc * 32 + fj * 16 + lr;
#pragma unroll
      for (int reg = 0; reg < 4; ++reg) {
        int row = wr * 32 + fi * 16 + lq * 4 + reg;
        int se = se_s[row], eu = eu_s[row];
        float xz = b2f(Xzh[(size_t)se * 1024 + colg]);
        float xh = b2f(Xzh[(size_t)se * 1024 + 512 + colg]);
        float sv = b2f(node_m[(size_t)se * HP + colg]) - b2f(mup[(size_t)eu * HP + colg]);
        float z = sigmoidf_(accZ[fi][fj][reg] + xz + biasp[colg]);
        float t = tanhf(accT[fi][fj][reg] + xh + biasp[512 + colg]);
        dtmp[(size_t)(m0 + row) * HP + colg] = f2b((1.f - z) * sv + z * t);
      }
    }
}

// ============== up-level GEMM2: r, rmup, pair-store node accumulators ==============
__global__ __launch_bounds__(256, 4) void mfma_lvl2_up(
    const int* __restrict__ schedrow, const int* __restrict__ dst,
    const u16* __restrict__ mup, u16* __restrict__ rmup,
    u16* __restrict__ node_m, u16* __restrict__ node_rm,
    const u16* __restrict__ Xr, const u16* __restrict__ UrT,
    const float* __restrict__ biasp) {
  __shared__ u16 Al[64 * 64], Bl[64 * 64];
  __shared__ int e_s[64], de_s[64];
  int tid = threadIdx.x;
  int n0 = blockIdx.x * 64, m0 = blockIdx.y * 64;
  if (tid < 64) { int e = schedrow[m0 + tid]; e_s[tid] = e; de_s[tid] = dst[e]; }
  __syncthreads();
  int l = tid & 63, w = tid >> 6, wr = w >> 1, wc = w & 1, lr = l & 15, lq = l >> 4;
  int sr = tid >> 2, skc = tid & 3;
  const u16* ab = mup + (size_t)e_s[sr] * HP + skc * 16;
  const u16* bb = UrT + (size_t)(n0 + sr) * HP + skc * 16;
  f32x4 acc[2][2] = {};
  for (int kt = 0; kt < HP; kt += 64) {
    *(bf16x8*)ldsp(Al, sr, 2 * skc) = ((const bf16x8*)(ab + kt))[0];
    *(bf16x8*)ldsp(Al, sr, 2 * skc + 1) = ((const bf16x8*)(ab + kt))[1];
    *(bf16x8*)ldsp(Bl, sr, 2 * skc) = ((const bf16x8*)(bb + kt))[0];
    *(bf16x8*)ldsp(Bl, sr, 2 * skc + 1) = ((const bf16x8*)(bb + kt))[1];
    __syncthreads();
#pragma unroll
    for (int kk = 0; kk < 64; kk += 32) {
      int slot = (kk >> 3) + lq;
      bf16x8 fa0 = *(bf16x8*)ldsp(Al, wr * 32 + lr, slot);
      bf16x8 fa1 = *(bf16x8*)ldsp(Al, wr * 32 + 16 + lr, slot);
      bf16x8 fb0 = *(bf16x8*)ldsp(Bl, wc * 32 + lr, slot);
      bf16x8 fb1 = *(bf16x8*)ldsp(Bl, wc * 32 + 16 + lr, slot);
      acc[0][0] = MFMA(fa0, fb0, acc[0][0]); acc[0][1] = MFMA(fa0, fb1, acc[0][1]);
      acc[1][0] = MFMA(fa1, fb0, acc[1][0]); acc[1][1] = MFMA(fa1, fb1, acc[1][1]);
    }
    __syncthreads();
  }
#pragma unroll
  for (int fi = 0; fi < 2; ++fi)
#pragma unroll
    for (int fj = 0; fj < 2; ++fj) {
      int colg = n0 + wc * 32 + fj * 16 + lr;
      int rowbase = wr * 32 + fi * 16 + lq * 4;
      float mv[4], rmv[4];
#pragma unroll
      for (int reg = 0; reg < 4; ++reg) {
        int row = rowbase + reg;
        int e = e_s[row], de = de_s[row];
        mv[reg] = b2f(mup[(size_t)e * HP + colg]);
        float r = sigmoidf_(acc[fi][fj][reg] + b2f(Xr[(size_t)de * HP + colg]) + biasp[1024 + colg]);
        rmv[reg] = r * mv[reg];
        rmup[(size_t)e * HP + colg] = f2b(rmv[reg]);
      }
      int de0 = de_s[rowbase], de2 = de_s[rowbase + 2];
      node_m[(size_t)de0 * HP + colg] = f2b(mv[0] + mv[1]);
      node_rm[(size_t)de0 * HP + colg] = f2b(rmv[0] + rmv[1]);
      node_m[(size_t)de2 * HP + colg] = f2b(mv[2] + mv[3]);
      node_rm[(size_t)de2 * HP + colg] = f2b(rmv[2] + rmv[3]);
    }
}

// ============== down-level GEMM2: r; node accumulators += ==============
__global__ __launch_bounds__(256, 4) void mfma_lvl2_down(
    const int* __restrict__ schedrow, const int* __restrict__ dst,
    const u16* __restrict__ dtmp,
    u16* __restrict__ node_m, u16* __restrict__ node_rm,
    const u16* __restrict__ Xr, const u16* __restrict__ UrT,
    const float* __restrict__ biasp) {
  __shared__ u16 Al[64 * 64], Bl[64 * 64];
  __shared__ int de_s[64];
  int tid = threadIdx.x;
  int n0 = blockIdx.x * 64, m0 = blockIdx.y * 64;
  if (tid < 64) de_s[tid] = dst[schedrow[m0 + tid]];
  __syncthreads();
  int l = tid & 63, w = tid >> 6, wr = w >> 1, wc = w & 1, lr = l & 15, lq = l >> 4;
  int sr = tid >> 2, skc = tid & 3;
  const u16* ab = dtmp + (size_t)(m0 + sr) * HP + skc * 16;
  const u16* bb = UrT + (size_t)(n0 + sr) * HP + skc * 16;
  f32x4 acc[2][2] = {};
  for (int kt = 0; kt < HP; kt += 64) {
    *(bf16x8*)ldsp(Al, sr, 2 * skc) = ((const bf16x8*)(ab + kt))[0];
    *(bf16x8*)ldsp(Al, sr, 2 * skc + 1) = ((const bf16x8*)(ab + kt))[1];
    *(bf16x8*)ldsp(Bl, sr, 2 * skc) = ((const bf16x8*)(bb + kt))[0];
    *(bf16x8*)ldsp(Bl, sr, 2 * skc + 1) = ((const bf16x8*)(bb + kt))[1];
    __syncthreads();
#pragma unroll
    for (int kk = 0; kk < 64; kk += 32) {
      int slot = (kk >> 3) + lq;
      bf16x8 fa0 = *(bf16x8*)ldsp(Al, wr * 32 + lr, slot);
      bf16x8 fa1 = *(bf16x8*)ldsp(Al, wr * 32 + 16 + lr, slot);
      bf16x8 fb0 = *(bf16x8*)ldsp(Bl, wc * 32 + lr, slot);
      bf16x8 fb1 = *(bf16x8*)ldsp(Bl, wc * 32 + 16 + lr, slot);
      acc[0][0] = MFMA(fa0, fb0, acc[0][0]); acc[0][1] = MFMA(fa0, fb1, acc[0][1]);
      acc[1][0] = MFMA(fa1, fb0, acc[1][0]); acc[1][1] = MFMA(fa1, fb1, acc[1][1]);
    }
    __syncthreads();
  }
#pragma unroll
  for (int fi = 0; fi < 2; ++fi)
#pragma unroll
    for (int fj = 0; fj < 2; ++fj) {
      int colg = n0 + wc * 32 + fj * 16 + lr;
#pragma unroll
      for (int reg = 0; reg < 4; ++reg) {
        int row = wr * 32 + fi * 16 + lq * 4 + reg;
        int de = de_s[row];
        size_t nidx = (size_t)de * HP + colg;
        float mv = b2f(dtmp[(size_t)(m0 + row) * HP + colg]);
        float r = sigmoidf_(acc[fi][fj][reg] + b2f(Xr[nidx]) + biasp[1024 + colg]);
        node_m[nidx] = f2b(b2f(node_m[nidx]) + mv);
        node_rm[nidx] = f2b(b2f(node_rm[nidx]) + r * mv);
      }
    }
}

// ============== final GEMM: h = relu([x, node_m] @ Wg + bg) ==============
__global__ __launch_bounds__(256, 4) void mfma_final(
    const u16* __restrict__ xp, const u16* __restrict__ node_m,
    const u16* __restrict__ WgT, const float* __restrict__ biasp,
    float* __restrict__ out) {
  __shared__ u16 Al[64 * 64], Bl[64 * 64];
  int tid = threadIdx.x;
  int n0 = blockIdx.x * 64, m0 = blockIdx.y * 64;
  int l = tid & 63, w = tid >> 6, wr = w >> 1, wc = w & 1, lr = l & 15, lq = l >> 4;
  int sr = tid >> 2, skc = tid & 3;
  const u16* axb = xp + (size_t)(m0 + sr) * HP + skc * 16;
  const u16* anb = node_m + (size_t)(m0 + sr) * HP + skc * 16;
  const u16* bb = WgT + (size_t)(n0 + sr) * 1024 + skc * 16;
  f32x4 acc[2][2] = {};
  for (int kt = 0; kt < 1024; kt += 64) {
    const u16* ap = (kt < HP) ? (axb + kt) : (anb + (kt - HP));
    *(bf16x8*)ldsp(Al, sr, 2 * skc) = ((const bf16x8*)ap)[0];
    *(bf16x8*)ldsp(Al, sr, 2 * skc + 1) = ((const bf16x8*)ap)[1];
    *(bf16x8*)ldsp(Bl, sr, 2 * skc) = ((const bf16x8*)(bb + kt))[0];
    *(bf16x8*)ldsp(Bl, sr, 2 * skc + 1) = ((const bf16x8*)(bb + kt))[1];
    __syncthreads();
#pragma unroll
    for (int kk = 0; kk < 64; kk += 32) {
      int slot = (kk >> 3) + lq;
      bf16x8 fa0 = *(bf16x8*)ldsp(Al, wr * 32 + lr, slot);
      bf16x8 fa1 = *(bf16x8*)ldsp(Al, wr * 32 + 16 + lr, slot);
      bf16x8 fb0 = *(bf16x8*)ldsp(Bl, wc * 32 + lr, slot);
      bf16x8 fb1 = *(bf16x8*)ldsp(Bl, wc * 32 + 16 + lr, slot);
      acc[0][0] = MFMA(fa0, fb0, acc[0][0]); acc[0][1] = MFMA(fa0, fb1, acc[0][1]);
      acc[1][0] = MFMA(fa1, fb0, acc[1][0]); acc[1][1] = MFMA(fa1, fb1, acc[1][1]);
    }
    __syncthreads();
  }
#pragma unroll
  for (int fi = 0; fi < 2; ++fi)
#pragma unroll
    for (int fj = 0; fj < 2; ++fj) {
      int colg = n0 + wc * 32 + fj * 16 + lr;
      if (colg >= HDIM) continue;
#pragma unroll
      for (int reg = 0; reg < 4; ++reg) {
        int row = m0 + wr * 32 + fi * 16 + lq * 4 + reg;
        float v = acc[fi][fj][reg] + biasp[1536 + colg];
        out[(size_t)row * HDIM + colg] = v > 0.f ? v : 0.f;
      }
    }
}

// ====================== host launcher ======================
extern "C" void kernel_launch(void* const* d_in, const int* in_sizes, int n_in,
                              void* d_out, int out_size, void* d_ws, size_t ws_size,
                              hipStream_t stream) {
  const int* wid = (const int*)d_in[0];
  const int* src = (const int*)d_in[1];
  const int* dst = (const int*)d_in[2];
  const int* sched = (const int*)d_in[4];
  const float* emb = (const float*)d_in[5];
  const float* Wz = (const float*)d_in[6];
  const float* bz = (const float*)d_in[7];
  const float* Wr = (const float*)d_in[8];
  const float* Ur = (const float*)d_in[9];
  const float* bur = (const float*)d_in[10];
  const float* Wh = (const float*)d_in[11];
  const float* bh = (const float*)d_in[12];
  const float* Wg = (const float*)d_in[13];
  const float* bg = (const float*)d_in[14];
  float* out = (float*)d_out;
  float* ws = (float*)d_ws;

  // ---- workspace layout (fp32 units); all state bf16 now, ~150 MB total ----
  size_t o = 0;
  u16* x_p = (u16*)(ws + o);     o += (size_t)NNODES * HP / 2;
  u16* Xzh = (u16*)(ws + o);     o += (size_t)NNODES * 1024 / 2;
  u16* Xr = (u16*)(ws + o);      o += (size_t)NNODES * HP / 2;
  u16* node_m = (u16*)(ws + o);  o += (size_t)NNODES * HP / 2;
  u16* node_rm = (u16*)(ws + o); o += (size_t)NNODES * HP / 2;
  u16* mup = (u16*)(ws + o);     o += (size_t)EUP * HP / 2;
  u16* rmup = (u16*)(ws + o);    o += (size_t)EUP * HP / 2;
  u16* dtmp = (u16*)(ws + o);    o += (size_t)LMAX * HP / 2;
  u16* WpreT = (u16*)(ws + o);   o += (size_t)1536 * HP / 2;
  u16* WzbT = (u16*)(ws + o);    o += (size_t)HP * HP / 2;
  u16* WhbT = (u16*)(ws + o);    o += (size_t)HP * HP / 2;
  u16* UrT = (u16*)(ws + o);     o += (size_t)HP * HP / 2;
  u16* WgT = (u16*)(ws + o);     o += (size_t)HP * 1024 / 2;
  float* biasp = ws + o;         o += (size_t)4 * HP;
  if (ws_size < o * sizeof(float)) return;  // diagnostic guard

  // zero node_m + node_rm (contiguous bf16 region = NNODES*HP*2*2 bytes)
  size_t zbytes = (size_t)2 * NNODES * HP * 2;
  zero_ws<<<2048, 256, 0, stream>>>((float4*)node_m, (int)(zbytes / 16));

  int prep_elems = 1536 * 512 + 3 * 262144 + 512 * 1024 + 4 * HP;
  prep_pad<<<(prep_elems + 255) / 256, 256, 0, stream>>>(
      Wz, Wh, Wr, Ur, Wg, bz, bh, bur, bg, WpreT, WzbT, WhbT, UrT, WgT, biasp);

  gather_embed<<<(NNODES * 64 + 255) / 256, 256, 0, stream>>>(wid, emb, x_p);

  mfma_pre<<<dim3(1536 / 64, NNODES / 64), 256, 0, stream>>>(x_p, WpreT, Xzh, Xr);

  for (int lvl = 0; lvl < NLVL; ++lvl) {
    int L = (lvl < 6) ? (LMAX >> lvl) : (256 << (lvl - 6));
    const int* schedrow = sched + (size_t)lvl * LMAX;
    if (lvl == 0) {
      leaf_lvl0<<<4096, 256, 0, stream>>>(schedrow, src, Xzh, biasp, mup);
    } else if (lvl < 6) {
      mfma_lvl1_up<<<dim3(8, L / 64), 256, 0, stream>>>(
          schedrow, src, node_m, node_rm, Xzh, WzbT, WhbT, biasp, mup);
    } else {
      mfma_lvl1_down<<<dim3(8, L / 64), 256, 0, stream>>>(
          schedrow, src, node_m, node_rm, mup, rmup, Xzh, WzbT, WhbT, biasp, dtmp);
    }
    if (lvl < 6) {
      mfma_lvl2_up<<<dim3(8, L / 64), 256, 0, stream>>>(
          schedrow, dst, mup, rmup, node_m, node_rm, Xr, UrT, biasp);
    } else {
      mfma_lvl2_down<<<dim3(8, L / 64), 256, 0, stream>>>(
          schedrow, dst, dtmp, node_m, node_rm, Xr, UrT, biasp);
    }
  }

  mfma_final<<<dim3(8, NNODES / 64), 256, 0, stream>>>(x_p, node_m, WgT, biasp, out);
}